// Round 14
// baseline (583.268 us; speedup 1.0000x reference)
//
#include <hip/hip_runtime.h>
#include <hip/hip_bf16.h>

#define NSEQ 512
#define NRES 768
#define MSAC 64
#define PAIRC 128
#define NHEAD 8

typedef __attribute__((ext_vector_type(8))) short short8_t;
typedef __attribute__((ext_vector_type(4))) float f32x4;

__device__ __forceinline__ float bf2f(unsigned short u){
  return __uint_as_float(((unsigned int)u) << 16);
}
__device__ __forceinline__ unsigned short f2bf(float f){
  unsigned int x = __float_as_uint(f);
  x += 0x7fffu + ((x >> 16) & 1u);   // RTNE
  return (unsigned short)(x >> 16);
}
// async global->LDS, 16B per lane; lds base wave-uniform (HW adds lane*16)
__device__ __forceinline__ void glds16(const void* g, void* l){
  __builtin_amdgcn_global_load_lds(
      (const __attribute__((address_space(1))) unsigned int*)g,
      (__attribute__((address_space(3))) unsigned int*)l, 16, 0, 0);
}

// -------- K0: mask max + weight prep (WvT/WgT/WoH/WoL + WST/AB for pair) --------
__global__ __launch_bounds__(256) void k_prep2(
    const float* __restrict__ mask, const float* __restrict__ vproj,
    const float* __restrict__ wgate, const float* __restrict__ wout,
    const float* __restrict__ pscale, const float* __restrict__ pbias,
    const float* __restrict__ wl,
    float* __restrict__ bias, unsigned short* __restrict__ WvT,
    unsigned short* __restrict__ WgT, unsigned short* __restrict__ WoH,
    unsigned short* __restrict__ WoL, unsigned short* __restrict__ WST,
    float* __restrict__ AB)
{
  const int bid = blockIdx.x, tid = threadIdx.x;
  if (bid < 12){
    __shared__ float red[4][64];
    const int kk = bid*64 + (tid & 63);
    const int bs = tid >> 6;
    float m = -1e30f;
    for (int b = bs; b < NSEQ; b += 4) m = fmaxf(m, mask[(size_t)b*NRES + kk]);
    red[bs][tid & 63] = m;
    __syncthreads();
    if (tid < 64){
      float mm = fmaxf(fmaxf(red[0][tid], red[1][tid]),
                       fmaxf(red[2][tid], red[3][tid]));
      bias[bid*64 + tid] = 1e9f * (bf2f(f2bf(mm)) - 1.0f);  // ref casts max to bf16
    }
  } else if (bid < 28){
    const int t = (bid - 12)*256 + tid;   // 4096 total
    const int j = t >> 6, i = t & 63;
    WvT[t] = f2bf(vproj[i*64 + j]);
    WgT[t] = f2bf(wgate[t]);
    float wv = wout[t];
    unsigned short hh = f2bf(wv);
    WoH[t] = hh;
    WoL[t] = f2bf(wv - bf2f(hh));
  } else {
    #pragma unroll
    for (int i = 0; i < 4; ++i){
      int t = i*256 + tid;              // 1024 entries
      int h = t >> 7, c = t & 127;
      float w = pscale[c] * wl[h*PAIRC + c];
      unsigned short hh = f2bf(w);
      WST[h*PAIRC + c] = hh;
      WST[(h + 8)*PAIRC + c] = f2bf(w - bf2f(hh));
    }
    const int h = tid >> 5, cc = tid & 31;
    float pa = 0.f, pb = 0.f;
    for (int c = cc; c < PAIRC; c += 32){
      float w = wl[h*PAIRC + c];
      pa += pscale[c]*w;  pb += pbias[c]*w;
    }
    #pragma unroll
    for (int m = 1; m < 32; m <<= 1){
      pa += __shfl_xor(pa, m, 64);
      pb += __shfl_xor(pb, m, 64);
    }
    if (cc == 0){ AB[h] = pa; AB[8 + h] = pb; }
  }
}

// ------- K1a: pair LN + MFMA logits + softmax (R12 body, x4 DIAGNOSTIC REP) -------
__global__ __launch_bounds__(256) void k_pair(
    const float* __restrict__ pair, const unsigned short* __restrict__ WST,
    const float* __restrict__ AB, const float* __restrict__ mbias,
    unsigned short* __restrict__ weights)
{
  __shared__ float lg[NHEAD][NRES];   // 24 KB
  const int q = blockIdx.x;
  const int tid = threadIdx.x;
  const int wv = tid >> 6, lane = tid & 63;
  const int lr = lane & 15, lcq = lane >> 4;

  short8_t wfrag[4];
  #pragma unroll
  for (int s = 0; s < 4; ++s)
    wfrag[s] = *(const short8_t*)(WST + lr*PAIRC + lcq*8 + s*32);

  const int hb = (lcq & 1) * 4;
  float A4[4], B4[4];
  #pragma unroll
  for (int r = 0; r < 4; ++r){ A4[r] = AB[hb + r]; B4[r] = AB[8 + hb + r]; }

  for (int rep = 0; rep < 4; ++rep){        // DIAGNOSTIC: idempotent x4
  __syncthreads();                          // rep isolation (uniform)
  for (int tile = wv; tile < 48; tile += 4){
    const int k0 = tile * 16;
    const float* base = pair + ((size_t)q*NRES + k0 + lr)*PAIRC + lcq*8;
    f32x4 a1 = 0.f, a2 = 0.f;
    float s = 0.f, ss = 0.f;
    #pragma unroll
    for (int st = 0; st < 4; ++st){
      float4 u0 = *(const float4*)(base + st*32);
      float4 u1 = *(const float4*)(base + st*32 + 4);
      float xv[8] = {u0.x,u0.y,u0.z,u0.w,u1.x,u1.y,u1.z,u1.w};
      short8_t xh, xl;
      #pragma unroll
      for (int e = 0; e < 8; ++e){
        s += xv[e]; ss += xv[e]*xv[e];
        unsigned short hi = f2bf(xv[e]);
        xh[e] = (short)hi;
        xl[e] = (short)f2bf(xv[e] - bf2f(hi));
      }
      a1 = __builtin_amdgcn_mfma_f32_16x16x32_bf16(wfrag[st], xh, a1, 0, 0, 0);
      a2 = __builtin_amdgcn_mfma_f32_16x16x32_bf16(wfrag[st], xl, a2, 0, 0, 0);
    }
    s  += __shfl_xor(s, 16, 64);  ss += __shfl_xor(ss, 16, 64);
    s  += __shfl_xor(s, 32, 64);  ss += __shfl_xor(ss, 32, 64);
    const float mu  = s * (1.f/128.f);
    const float var = ss * (1.f/128.f) - mu*mu;
    const float rsq = rsqrtf(var + 1e-5f);
    float d[4];
    #pragma unroll
    for (int r = 0; r < 4; ++r)
      d[r] = a1[r] + __shfl_xor(a1[r], 32, 64) + a2[r];
    if (lane < 32){
      const int k = k0 + lr;
      #pragma unroll
      for (int r = 0; r < 4; ++r)
        lg[hb + r][k] = rsq * (d[r] - mu * A4[r]) + B4[r];
    }
  }
  __syncthreads();
  #pragma unroll
  for (int hh = 0; hh < 2; ++hh){
    int h = wv + hh*4;
    float mx = -1e30f;
    for (int kk = lane; kk < NRES; kk += 64) mx = fmaxf(mx, lg[h][kk] + mbias[kk]);
    #pragma unroll
    for (int m = 1; m < 64; m <<= 1) mx = fmaxf(mx, __shfl_xor(mx, m, 64));
    float sum = 0.f;
    for (int kk = lane; kk < NRES; kk += 64){
      float e = __expf(lg[h][kk] + mbias[kk] - mx);
      lg[h][kk] = e; sum += e;
    }
    #pragma unroll
    for (int m = 1; m < 64; m <<= 1) sum += __shfl_xor(sum, m, 64);
    float inv = 1.0f / sum;
    unsigned short* wrow = weights + ((size_t)h * NRES + q) * NRES;
    for (int kk = lane; kk < NRES; kk += 64) wrow[kk] = f2bf(lg[h][kk] * inv);
  }
  asm volatile("" ::: "memory");            // force re-load next rep
  }
}

// ------- K1b: act LN + v/gate register-direct MFMA (R12 body, x4 DIAGNOSTIC REP) -------
__global__ __launch_bounds__(512) void k_act(
    const float* __restrict__ act, const float* __restrict__ ascale,
    const float* __restrict__ abias, const unsigned short* __restrict__ WvT,
    const unsigned short* __restrict__ WgT, unsigned short* __restrict__ v,
    unsigned short* __restrict__ gate)
{
  __shared__ __align__(16) unsigned char sm[18432];
  unsigned short (*vt)[72] = (unsigned short (*)[72])sm;            // 9216 B
  unsigned short (*gt)[72] = (unsigned short (*)[72])(sm + 9216);   // 9216 B
  const int abid = blockIdx.x;
  const int b  = abid / 6;
  const int k0 = (abid % 6) * 128;
  const int tid = threadIdx.x;
  const int w = tid >> 6, lane = tid & 63;   // w in [0,8)
  const int lr = lane & 15;
  const int lc = lane >> 4;
  const int row = k0 + w*16 + lr;

  for (int rep = 0; rep < 4; ++rep){        // DIAGNOSTIC: idempotent x4
  __syncthreads();
  short8_t bv[4][2], bg[4][2];
  #pragma unroll
  for (int mf = 0; mf < 4; ++mf){
    #pragma unroll
    for (int s = 0; s < 2; ++s){
      bv[mf][s] = *(const short8_t*)(WvT + (mf*16 + lr)*64 + s*32 + lc*8);
      bg[mf][s] = *(const short8_t*)(WgT + (mf*16 + lr)*64 + s*32 + lc*8);
    }
  }

  const float* arow = act + ((size_t)b*NRES + row)*MSAC;
  float x[2][8];
  #pragma unroll
  for (int s = 0; s < 2; ++s){
    float4 t0 = *(const float4*)(arow + s*32 + lc*8);
    float4 t1 = *(const float4*)(arow + s*32 + lc*8 + 4);
    x[s][0]=t0.x; x[s][1]=t0.y; x[s][2]=t0.z; x[s][3]=t0.w;
    x[s][4]=t1.x; x[s][5]=t1.y; x[s][6]=t1.z; x[s][7]=t1.w;
  }
  float ps = 0.f, pss = 0.f;
  #pragma unroll
  for (int s = 0; s < 2; ++s)
    #pragma unroll
    for (int e = 0; e < 8; ++e){ ps += x[s][e]; pss += x[s][e]*x[s][e]; }
  ps  += __shfl_xor(ps, 16, 64);  pss += __shfl_xor(pss, 16, 64);
  ps  += __shfl_xor(ps, 32, 64);  pss += __shfl_xor(pss, 32, 64);
  const float mu  = ps * (1.f/64.f);
  const float var = pss * (1.f/64.f) - mu*mu;
  const float rs  = rsqrtf(var + 1e-5f);

  short8_t a[2];
  #pragma unroll
  for (int s = 0; s < 2; ++s){
    float4 s0 = *(const float4*)(ascale + s*32 + lc*8);
    float4 s1 = *(const float4*)(ascale + s*32 + lc*8 + 4);
    float4 b0 = *(const float4*)(abias  + s*32 + lc*8);
    float4 b1 = *(const float4*)(abias  + s*32 + lc*8 + 4);
    const float sc[8] = {s0.x,s0.y,s0.z,s0.w,s1.x,s1.y,s1.z,s1.w};
    const float bs[8] = {b0.x,b0.y,b0.z,b0.w,b1.x,b1.y,b1.z,b1.w};
    #pragma unroll
    for (int e = 0; e < 8; ++e)
      a[s][e] = (short)f2bf((x[s][e] - mu)*rs*sc[e] + bs[e]);
  }

  f32x4 accv[4], accg[4];
  #pragma unroll
  for (int mf = 0; mf < 4; ++mf){ accv[mf] = 0.f; accg[mf] = 0.f; }
  #pragma unroll
  for (int mf = 0; mf < 4; ++mf){
    #pragma unroll
    for (int s = 0; s < 2; ++s){
      accv[mf] = __builtin_amdgcn_mfma_f32_16x16x32_bf16(a[s], bv[mf][s], accv[mf], 0, 0, 0);
      accg[mf] = __builtin_amdgcn_mfma_f32_16x16x32_bf16(bg[mf][s], a[s], accg[mf], 0, 0, 0);
    }
  }

  // two-pass epilogue through 18 KB LDS: rows 0-63 (waves 0-3), rows 64-127 (4-7)
  #pragma unroll
  for (int pass = 0; pass < 2; ++pass){
    if ((w >> 2) == pass){
      const int wl2 = w & 3;
      #pragma unroll
      for (int mf = 0; mf < 4; ++mf){
        ushort4 ov;
        ov.x = f2bf(accv[mf][0]); ov.y = f2bf(accv[mf][1]);
        ov.z = f2bf(accv[mf][2]); ov.w = f2bf(accv[mf][3]);
        *(ushort4*)&vt[mf*16 + lr][wl2*16 + lc*4] = ov;
        ushort4 og;
        og.x = f2bf(1.0f/(1.0f + __expf(-accg[mf][0])));
        og.y = f2bf(1.0f/(1.0f + __expf(-accg[mf][1])));
        og.z = f2bf(1.0f/(1.0f + __expf(-accg[mf][2])));
        og.w = f2bf(1.0f/(1.0f + __expf(-accg[mf][3])));
        *(ushort4*)&gt[wl2*16 + lr][mf*16 + lc*4] = og;
      }
    }
    __syncthreads();
    {
      const int kbase = k0 + pass*64;
      const int j = tid >> 3, chunk = tid & 7;       // 512 threads cover [64][8]
      uint4 val = *(const uint4*)&vt[j][chunk*8];
      *(uint4*)(v + ((size_t)(j >> 3)*4096 + (size_t)b*8 + (j & 7))*NRES + kbase + chunk*8) = val;
      uint4 gval = *(const uint4*)&gt[j][chunk*8];   // j = local k row here
      *(uint4*)(gate + ((size_t)b*NRES + kbase + j)*MSAC + chunk*8) = gval;
    }
    __syncthreads();
  }
  asm volatile("" ::: "memory");
  }
}

// ------- K4: per-head GEMM  Y3[h][bx][q][cl] = weights[h] @ v[h] -------
// 2-phase double-buffered pipeline, BK=32, single barrier per K-step.
__global__ __launch_bounds__(256) void k_wavg(
    const unsigned short* __restrict__ V, const unsigned short* __restrict__ W,
    unsigned short* __restrict__ Y)
{
  __shared__ unsigned char smem[32768];

  const int flat = blockIdx.x;
  const int nid  = (flat & 7) * 192 + (flat >> 3);   // XCD chunk of 192 = 1 head
  const int m    = nid % 192;
  const int by   = m % 6;              // fastest: A-tile reuse across 6 blocks
  const int bx   = m / 6;
  const int h    = nid / 192;

  const int tid = threadIdx.x, wid = tid >> 6, lane = tid & 63;
  const int wm = wid & 1, wn = wid >> 1;
  const unsigned short* Ag = V + (size_t)h*4096*768 + (size_t)bx*128*768;
  const unsigned short* Bg = W + (size_t)h*768*768 + (size_t)by*128*768;

  f32x4 acc[4][4];
  #pragma unroll
  for (int i=0;i<4;++i){
    #pragma unroll
    for (int jj=0;jj<4;++jj) acc[i][jj] = 0.f;
  }

  #define STAGE_K(bufsel, kt) { \
    unsigned char* Ab = smem + (bufsel)*16384; \
    unsigned char* Bb = Ab + 8192; \
    _Pragma("unroll") \
    for (int r = 0; r < 2; ++r){ \
      int cid = tid + r*256; \
      int rw = cid >> 2, ch = cid & 3; \
      int sc = ch ^ ((rw >> 1) & 3); \
      glds16(Ag + (size_t)rw*768 + (kt)*32 + sc*8, Ab + cid*16 - lane*16); \
      glds16(Bg + (size_t)rw*768 + (kt)*32 + sc*8, Bb + cid*16 - lane*16); \
    } }

  STAGE_K(0, 0);
  __syncthreads();
  const int c0 = lane >> 4;            // k-chunk selector
  for (int kt = 0; kt < 24; ++kt){
    if (kt < 23) STAGE_K((kt+1)&1, kt+1);     // prefetch overlaps compute below
    unsigned char* Ab = smem + (kt&1)*16384;
    unsigned char* Bb = Ab + 8192;
    short8_t af[4], bf[4];
    #pragma unroll
    for (int mf = 0; mf < 4; ++mf){
      int row = wm*64 + mf*16 + (lane & 15);
      int off = row*64 + ((c0 ^ ((row>>1)&3)) << 4);
      af[mf] = *(const short8_t*)(Ab + off);
    }
    #pragma unroll
    for (int nf = 0; nf < 4; ++nf){
      int row = wn*64 + nf*16 + (lane & 15);
      int off = row*64 + ((c0 ^ ((row>>1)&3)) << 4);
      bf[nf] = *(const short8_t*)(Bb + off);
    }
    #pragma unroll
    for (int mf = 0; mf < 4; ++mf){
      #pragma unroll
      for (int nf = 0; nf < 4; ++nf)
        acc[mf][nf] = __builtin_amdgcn_mfma_f32_16x16x32_bf16(af[mf], bf[nf], acc[mf][nf], 0, 0, 0);
    }
    __syncthreads();   // single drain per step
  }
  #undef STAGE_K

  // ---- epilogue: D -> swizzled LDS (aliases bufs) -> contiguous 32 KB store ----
  unsigned char* Ds = smem;              // 32 KB: [q_local 128][bc_local 128] bf16
  #pragma unroll
  for (int mf = 0; mf < 4; ++mf){
    int bc = wm*64 + mf*16 + ((lane >> 4) << 2);
    #pragma unroll
    for (int nf = 0; nf < 4; ++nf){
      int q = wn*64 + nf*16 + (lane & 15);
      f32x4 a = acc[mf][nf];
      ushort4 o;
      o.x = f2bf(a[0]); o.y = f2bf(a[1]); o.z = f2bf(a[2]); o.w = f2bf(a[3]);
      int off = q*256 + bc*2; off ^= (q & 7) << 4;
      *(ushort4*)(Ds + off) = o;
    }
  }
  __syncthreads();
  unsigned short* Yb = Y + ((size_t)(h*32 + bx)*768 + by*128)*128;
  #pragma unroll
  for (int it = 0; it < 8; ++it){
    int fl = it*256 + tid;
    int q = fl >> 4, chunk = fl & 15;
    int off = q*256 + chunk*16; off ^= (q & 7) << 4;
    uint4 val = *(const uint4*)(Ds + off);
    *(uint4*)(Yb + (size_t)fl*8) = val;
  }
}

// ------- K5: out[b][q][:] = (y*gate) @ wout^T via MFMA (hi/lo split) -------
__global__ __launch_bounds__(256) void k_final(
    const unsigned short* __restrict__ Y, const unsigned short* __restrict__ gate,
    const unsigned short* __restrict__ WoH, const unsigned short* __restrict__ WoL,
    float* __restrict__ out)
{
  const int p = blockIdx.x;
  const int r = p & 7, t = p >> 3;
  const int b  = r*64 + (t & 63);
  const int q0 = (t >> 6) * 64;
  const int tid = threadIdx.x, w = tid >> 6, lane = tid & 63;
  const int lr = lane & 15, lc = lane >> 4;

  short8_t bh[4][2], bl[4][2];
  #pragma unroll
  for (int nf = 0; nf < 4; ++nf){
    #pragma unroll
    for (int s = 0; s < 2; ++s){
      bh[nf][s] = *(const short8_t*)(WoH + (nf*16 + lr)*64 + s*32 + lc*8);
      bl[nf][s] = *(const short8_t*)(WoL + (nf*16 + lr)*64 + s*32 + lc*8);
    }
  }

  const int q = q0 + w*16 + lr;
  short8_t ah[2], al[2];
  #pragma unroll
  for (int s = 0; s < 2; ++s){
    const int hh = s*4 + lc;          // head = i>>3
    short8_t y8 = *(const short8_t*)(Y + ((size_t)(hh*32 + (b >> 4))*768 + q)*128 + (b & 15)*8);
    short8_t g8 = *(const short8_t*)(gate + ((size_t)b*NRES + q)*MSAC + s*32 + lc*8);
    #pragma unroll
    for (int e = 0; e < 8; ++e){
      float pp = bf2f((unsigned short)y8[e]) * bf2f((unsigned short)g8[e]);
      unsigned short hi = f2bf(pp);
      ah[s][e] = (short)hi;
      al[s][e] = (short)f2bf(pp - bf2f(hi));
    }
  }

  f32x4 acc[4];
  #pragma unroll
  for (int nf = 0; nf < 4; ++nf) acc[nf] = 0.f;
  #pragma unroll
  for (int nf = 0; nf < 4; ++nf){
    #pragma unroll
    for (int s = 0; s < 2; ++s){
      acc[nf] = __builtin_amdgcn_mfma_f32_16x16x32_bf16(ah[s], bh[nf][s], acc[nf], 0, 0, 0);
      acc[nf] = __builtin_amdgcn_mfma_f32_16x16x32_bf16(al[s], bh[nf][s], acc[nf], 0, 0, 0);
      acc[nf] = __builtin_amdgcn_mfma_f32_16x16x32_bf16(ah[s], bl[nf][s], acc[nf], 0, 0, 0);
    }
  }

  #pragma unroll
  for (int nf = 0; nf < 4; ++nf){
    #pragma unroll
    for (int e = 0; e < 4; ++e){
      int qq = q0 + w*16 + lc*4 + e;
      out[((size_t)b*NRES + qq)*MSAC + nf*16 + lr] = acc[nf][e];
    }
  }
}

extern "C" void kernel_launch(void* const* d_in, const int* in_sizes, int n_in,
                              void* d_out, int out_size, void* d_ws, size_t ws_size,
                              hipStream_t stream) {
  (void)in_sizes; (void)n_in; (void)out_size; (void)ws_size;
  const float* act    = (const float*)d_in[0];
  const float* mask   = (const float*)d_in[1];
  const float* pair   = (const float*)d_in[2];
  const float* ascale = (const float*)d_in[3];
  const float* abias  = (const float*)d_in[4];
  const float* pscale = (const float*)d_in[5];
  const float* pbias  = (const float*)d_in[6];
  const float* wl     = (const float*)d_in[7];
  const float* vproj  = (const float*)d_in[8];
  const float* wgate  = (const float*)d_in[9];
  const float* wout   = (const float*)d_in[10];
  float* out = (float*)d_out;

  char* ws = (char*)d_ws;
  float*          mbias   = (float*)(ws);                                   // 3 KB
  unsigned short* WvT     = (unsigned short*)(ws + 4096);                   // 8 KB
  unsigned short* WgT     = (unsigned short*)(ws + 12288);                  // 8 KB
  unsigned short* WoH     = (unsigned short*)(ws + 20480);                  // 8 KB
  unsigned short* WoL     = (unsigned short*)(ws + 28672);                  // 8 KB
  unsigned short* WST     = (unsigned short*)(ws + 36864);                  // 4 KB
  float*          AB      = (float*)(ws + 40960);                           // 64 B
  unsigned short* weights = (unsigned short*)(ws + 45056);                  // 9.4 MB  [h][q][k]
  unsigned short* v       = (unsigned short*)(ws + 45056 + 9437184);        // 50.3 MB [h][bc][k]
  unsigned short* gate    = (unsigned short*)(ws + 45056 + 9437184 + 50331648);       // 50.3 MB [b][k][64]
  unsigned short* y       = (unsigned short*)(ws + 45056 + 9437184 + 2*50331648ull);  // 50.3 MB [h][bx][q][cl]

  k_prep2<<<dim3(29), dim3(256), 0, stream>>>(mask, vproj, wgate, wout,
                                              pscale, pbias, wl,
                                              mbias, WvT, WgT, WoH, WoL, WST, AB);
  k_pair<<<dim3(768), dim3(256), 0, stream>>>(pair, WST, AB, mbias, weights);
  k_act<<<dim3(3072), dim3(512), 0, stream>>>(act, ascale, abias, WvT, WgT, v, gate);
  k_wavg<<<dim3(1536), dim3(256), 0, stream>>>(v, weights, y);
  k_final<<<dim3(6144), dim3(256), 0, stream>>>(y, gate, WoH, WoL, out);
}

// Round 15
// 317.492 us; speedup vs baseline: 1.8371x; 1.8371x over previous
//
#include <hip/hip_runtime.h>
#include <hip/hip_bf16.h>

#define NSEQ 512
#define NRES 768
#define MSAC 64
#define PAIRC 128
#define NHEAD 8

typedef __attribute__((ext_vector_type(8))) short short8_t;
typedef __attribute__((ext_vector_type(4))) float f32x4;

__device__ __forceinline__ float bf2f(unsigned short u){
  return __uint_as_float(((unsigned int)u) << 16);
}
__device__ __forceinline__ unsigned short f2bf(float f){
  unsigned int x = __float_as_uint(f);
  x += 0x7fffu + ((x >> 16) & 1u);   // RTNE
  return (unsigned short)(x >> 16);
}
// async global->LDS, 16B per lane; lds base wave-uniform (HW adds lane*16)
__device__ __forceinline__ void glds16(const void* g, void* l){
  __builtin_amdgcn_global_load_lds(
      (const __attribute__((address_space(1))) unsigned int*)g,
      (__attribute__((address_space(3))) unsigned int*)l, 16, 0, 0);
}

// -------- K0: mask max + weight prep (WvT/WgT/WoH/WoL + WST/AB for pair) --------
__global__ __launch_bounds__(256) void k_prep2(
    const float* __restrict__ mask, const float* __restrict__ vproj,
    const float* __restrict__ wgate, const float* __restrict__ wout,
    const float* __restrict__ pscale, const float* __restrict__ pbias,
    const float* __restrict__ wl,
    float* __restrict__ bias, unsigned short* __restrict__ WvT,
    unsigned short* __restrict__ WgT, unsigned short* __restrict__ WoH,
    unsigned short* __restrict__ WoL, unsigned short* __restrict__ WST,
    float* __restrict__ AB)
{
  const int bid = blockIdx.x, tid = threadIdx.x;
  if (bid < 12){
    __shared__ float red[4][64];
    const int kk = bid*64 + (tid & 63);
    const int bs = tid >> 6;
    float m = -1e30f;
    for (int b = bs; b < NSEQ; b += 4) m = fmaxf(m, mask[(size_t)b*NRES + kk]);
    red[bs][tid & 63] = m;
    __syncthreads();
    if (tid < 64){
      float mm = fmaxf(fmaxf(red[0][tid], red[1][tid]),
                       fmaxf(red[2][tid], red[3][tid]));
      bias[bid*64 + tid] = 1e9f * (bf2f(f2bf(mm)) - 1.0f);  // ref casts max to bf16
    }
  } else if (bid < 28){
    const int t = (bid - 12)*256 + tid;   // 4096 total
    const int j = t >> 6, i = t & 63;
    WvT[t] = f2bf(vproj[i*64 + j]);
    WgT[t] = f2bf(wgate[t]);
    float wv = wout[t];
    unsigned short hh = f2bf(wv);
    WoH[t] = hh;
    WoL[t] = f2bf(wv - bf2f(hh));
  } else {
    #pragma unroll
    for (int i = 0; i < 4; ++i){
      int t = i*256 + tid;              // 1024 entries
      int h = t >> 7, c = t & 127;
      float w = pscale[c] * wl[h*PAIRC + c];
      unsigned short hh = f2bf(w);
      WST[h*PAIRC + c] = hh;
      WST[(h + 8)*PAIRC + c] = f2bf(w - bf2f(hh));
    }
    const int h = tid >> 5, cc = tid & 31;
    float pa = 0.f, pb = 0.f;
    for (int c = cc; c < PAIRC; c += 32){
      float w = wl[h*PAIRC + c];
      pa += pscale[c]*w;  pb += pbias[c]*w;
    }
    #pragma unroll
    for (int m = 1; m < 32; m <<= 1){
      pa += __shfl_xor(pa, m, 64);
      pb += __shfl_xor(pb, m, 64);
    }
    if (cc == 0){ AB[h] = pa; AB[8 + h] = pb; }
  }
}

// ------- K1a: pair LN + MFMA logits -> logits f32 [q][h][k] -------
// SPLIT-K grid: 3072 blocks = (q, k-quarter). 3 tiles/wave, ZERO LDS ->
// occupancy VGPR-bound only (8 blocks/CU = 32 waves/CU vs old 3 blocks/CU).
__global__ __launch_bounds__(256) void k_pair(
    const float* __restrict__ pair, const unsigned short* __restrict__ WST,
    const float* __restrict__ AB, float* __restrict__ logits)
{
  const int q = blockIdx.x >> 2;
  const int quarter = blockIdx.x & 3;
  const int tid = threadIdx.x;
  const int wv = tid >> 6, lane = tid & 63;
  const int lr = lane & 15, lcq = lane >> 4;

  short8_t wfrag[4];
  #pragma unroll
  for (int s = 0; s < 4; ++s)
    wfrag[s] = *(const short8_t*)(WST + lr*PAIRC + lcq*8 + s*32);

  const int hb = (lcq & 1) * 4;
  float A4[4], B4[4];
  #pragma unroll
  for (int r = 0; r < 4; ++r){ A4[r] = AB[hb + r]; B4[r] = AB[8 + hb + r]; }

  #pragma unroll
  for (int i = 0; i < 3; ++i){
    const int tile = quarter*12 + wv + 4*i;
    const int k0 = tile * 16;
    const float* base = pair + ((size_t)q*NRES + k0 + lr)*PAIRC + lcq*8;
    f32x4 a1 = 0.f, a2 = 0.f;
    float s = 0.f, ss = 0.f;
    #pragma unroll
    for (int st = 0; st < 4; ++st){
      float4 u0 = *(const float4*)(base + st*32);
      float4 u1 = *(const float4*)(base + st*32 + 4);
      float xv[8] = {u0.x,u0.y,u0.z,u0.w,u1.x,u1.y,u1.z,u1.w};
      short8_t xh, xl;
      #pragma unroll
      for (int e = 0; e < 8; ++e){
        s += xv[e]; ss += xv[e]*xv[e];
        unsigned short hi = f2bf(xv[e]);
        xh[e] = (short)hi;
        xl[e] = (short)f2bf(xv[e] - bf2f(hi));
      }
      a1 = __builtin_amdgcn_mfma_f32_16x16x32_bf16(wfrag[st], xh, a1, 0, 0, 0);
      a2 = __builtin_amdgcn_mfma_f32_16x16x32_bf16(wfrag[st], xl, a2, 0, 0, 0);
    }
    s  += __shfl_xor(s, 16, 64);  ss += __shfl_xor(ss, 16, 64);
    s  += __shfl_xor(s, 32, 64);  ss += __shfl_xor(ss, 32, 64);
    const float mu  = s * (1.f/128.f);
    const float var = ss * (1.f/128.f) - mu*mu;
    const float rsq = rsqrtf(var + 1e-5f);
    float d[4];
    #pragma unroll
    for (int r = 0; r < 4; ++r)
      d[r] = a1[r] + __shfl_xor(a1[r], 32, 64) + a2[r];
    if (lane < 32){
      const int k = k0 + lr;
      #pragma unroll
      for (int r = 0; r < 4; ++r)
        logits[(size_t)q*6144 + (hb + r)*768 + k] = rsq * (d[r] - mu * A4[r]) + B4[r];
    }
  }
}

// ------- K1s: softmax over k: logits[q][h][k] + mbias -> weights bf16 [h][q][k] -------
__global__ __launch_bounds__(256) void k_soft(
    const float* __restrict__ logits, const float* __restrict__ mbias,
    unsigned short* __restrict__ weights)
{
  __shared__ float lgf[6144];   // 24 KB: [h][k] for this q
  const int q = blockIdx.x, tid = threadIdx.x;
  const float* src = logits + (size_t)q*6144;
  #pragma unroll
  for (int i = 0; i < 6; ++i){
    int idx = (i*256 + tid)*4;
    *(float4*)&lgf[idx] = *(const float4*)(src + idx);
  }
  __syncthreads();
  const int wv = tid >> 6, lane = tid & 63;
  #pragma unroll
  for (int hh = 0; hh < 2; ++hh){
    int h = wv + hh*4;
    float mx = -1e30f;
    for (int kk = lane; kk < NRES; kk += 64) mx = fmaxf(mx, lgf[h*768 + kk] + mbias[kk]);
    #pragma unroll
    for (int m = 1; m < 64; m <<= 1) mx = fmaxf(mx, __shfl_xor(mx, m, 64));
    float sum = 0.f;
    for (int kk = lane; kk < NRES; kk += 64){
      float e = __expf(lgf[h*768 + kk] + mbias[kk] - mx);
      lgf[h*768 + kk] = e; sum += e;
    }
    #pragma unroll
    for (int m = 1; m < 64; m <<= 1) sum += __shfl_xor(sum, m, 64);
    float inv = 1.0f / sum;
    unsigned short* wrow = weights + ((size_t)h * NRES + q) * NRES;
    for (int kk = lane; kk < NRES; kk += 64) wrow[kk] = f2bf(lgf[h*768 + kk] * inv);
  }
}

// ------- K1b: act LN + v/gate via register-direct MFMA (512 thr, 128 rows) -------
__global__ __launch_bounds__(512) void k_act(
    const float* __restrict__ act, const float* __restrict__ ascale,
    const float* __restrict__ abias, const unsigned short* __restrict__ WvT,
    const unsigned short* __restrict__ WgT, unsigned short* __restrict__ v,
    unsigned short* __restrict__ gate)
{
  __shared__ __align__(16) unsigned char sm[18432];
  unsigned short (*vt)[72] = (unsigned short (*)[72])sm;            // 9216 B
  unsigned short (*gt)[72] = (unsigned short (*)[72])(sm + 9216);   // 9216 B
  const int abid = blockIdx.x;
  const int b  = abid / 6;
  const int k0 = (abid % 6) * 128;
  const int tid = threadIdx.x;
  const int w = tid >> 6, lane = tid & 63;   // w in [0,8)
  const int lr = lane & 15;
  const int lc = lane >> 4;
  const int row = k0 + w*16 + lr;

  short8_t bv[4][2], bg[4][2];
  #pragma unroll
  for (int mf = 0; mf < 4; ++mf){
    #pragma unroll
    for (int s = 0; s < 2; ++s){
      bv[mf][s] = *(const short8_t*)(WvT + (mf*16 + lr)*64 + s*32 + lc*8);
      bg[mf][s] = *(const short8_t*)(WgT + (mf*16 + lr)*64 + s*32 + lc*8);
    }
  }

  const float* arow = act + ((size_t)b*NRES + row)*MSAC;
  float x[2][8];
  #pragma unroll
  for (int s = 0; s < 2; ++s){
    float4 t0 = *(const float4*)(arow + s*32 + lc*8);
    float4 t1 = *(const float4*)(arow + s*32 + lc*8 + 4);
    x[s][0]=t0.x; x[s][1]=t0.y; x[s][2]=t0.z; x[s][3]=t0.w;
    x[s][4]=t1.x; x[s][5]=t1.y; x[s][6]=t1.z; x[s][7]=t1.w;
  }
  float ps = 0.f, pss = 0.f;
  #pragma unroll
  for (int s = 0; s < 2; ++s)
    #pragma unroll
    for (int e = 0; e < 8; ++e){ ps += x[s][e]; pss += x[s][e]*x[s][e]; }
  ps  += __shfl_xor(ps, 16, 64);  pss += __shfl_xor(pss, 16, 64);
  ps  += __shfl_xor(ps, 32, 64);  pss += __shfl_xor(pss, 32, 64);
  const float mu  = ps * (1.f/64.f);
  const float var = pss * (1.f/64.f) - mu*mu;
  const float rs  = rsqrtf(var + 1e-5f);

  short8_t a[2];
  #pragma unroll
  for (int s = 0; s < 2; ++s){
    float4 s0 = *(const float4*)(ascale + s*32 + lc*8);
    float4 s1 = *(const float4*)(ascale + s*32 + lc*8 + 4);
    float4 b0 = *(const float4*)(abias  + s*32 + lc*8);
    float4 b1 = *(const float4*)(abias  + s*32 + lc*8 + 4);
    const float sc[8] = {s0.x,s0.y,s0.z,s0.w,s1.x,s1.y,s1.z,s1.w};
    const float bs[8] = {b0.x,b0.y,b0.z,b0.w,b1.x,b1.y,b1.z,b1.w};
    #pragma unroll
    for (int e = 0; e < 8; ++e)
      a[s][e] = (short)f2bf((x[s][e] - mu)*rs*sc[e] + bs[e]);
  }

  f32x4 accv[4], accg[4];
  #pragma unroll
  for (int mf = 0; mf < 4; ++mf){ accv[mf] = 0.f; accg[mf] = 0.f; }
  #pragma unroll
  for (int mf = 0; mf < 4; ++mf){
    #pragma unroll
    for (int s = 0; s < 2; ++s){
      accv[mf] = __builtin_amdgcn_mfma_f32_16x16x32_bf16(a[s], bv[mf][s], accv[mf], 0, 0, 0);
      accg[mf] = __builtin_amdgcn_mfma_f32_16x16x32_bf16(bg[mf][s], a[s], accg[mf], 0, 0, 0);
    }
  }

  // two-pass epilogue through 18 KB LDS: rows 0-63 (waves 0-3), rows 64-127 (4-7)
  #pragma unroll
  for (int pass = 0; pass < 2; ++pass){
    if ((w >> 2) == pass){
      const int wl2 = w & 3;
      #pragma unroll
      for (int mf = 0; mf < 4; ++mf){
        ushort4 ov;
        ov.x = f2bf(accv[mf][0]); ov.y = f2bf(accv[mf][1]);
        ov.z = f2bf(accv[mf][2]); ov.w = f2bf(accv[mf][3]);
        *(ushort4*)&vt[mf*16 + lr][wl2*16 + lc*4] = ov;
        ushort4 og;
        og.x = f2bf(1.0f/(1.0f + __expf(-accg[mf][0])));
        og.y = f2bf(1.0f/(1.0f + __expf(-accg[mf][1])));
        og.z = f2bf(1.0f/(1.0f + __expf(-accg[mf][2])));
        og.w = f2bf(1.0f/(1.0f + __expf(-accg[mf][3])));
        *(ushort4*)&gt[wl2*16 + lr][mf*16 + lc*4] = og;
      }
    }
    __syncthreads();
    {
      const int kbase = k0 + pass*64;
      const int j = tid >> 3, chunk = tid & 7;       // 512 threads cover [64][8]
      uint4 val = *(const uint4*)&vt[j][chunk*8];
      *(uint4*)(v + ((size_t)(j >> 3)*4096 + (size_t)b*8 + (j & 7))*NRES + kbase + chunk*8) = val;
      uint4 gval = *(const uint4*)&gt[j][chunk*8];   // j = local k row here
      *(uint4*)(gate + ((size_t)b*NRES + kbase + j)*MSAC + chunk*8) = gval;
    }
    __syncthreads();
  }
}

// ------- K4: per-head GEMM  Y3[h][bx][q][cl] = weights[h] @ v[h] -------
// 2-phase double-buffered pipeline, BK=32, single barrier per K-step.
__global__ __launch_bounds__(256) void k_wavg(
    const unsigned short* __restrict__ V, const unsigned short* __restrict__ W,
    unsigned short* __restrict__ Y)
{
  __shared__ unsigned char smem[32768];

  const int flat = blockIdx.x;
  const int nid  = (flat & 7) * 192 + (flat >> 3);   // XCD chunk of 192 = 1 head
  const int m    = nid % 192;
  const int by   = m % 6;              // fastest: A-tile reuse across 6 blocks
  const int bx   = m / 6;
  const int h    = nid / 192;

  const int tid = threadIdx.x, wid = tid >> 6, lane = tid & 63;
  const int wm = wid & 1, wn = wid >> 1;
  const unsigned short* Ag = V + (size_t)h*4096*768 + (size_t)bx*128*768;
  const unsigned short* Bg = W + (size_t)h*768*768 + (size_t)by*128*768;

  f32x4 acc[4][4];
  #pragma unroll
  for (int i=0;i<4;++i){
    #pragma unroll
    for (int jj=0;jj<4;++jj) acc[i][jj] = 0.f;
  }

  #define STAGE_K(bufsel, kt) { \
    unsigned char* Ab = smem + (bufsel)*16384; \
    unsigned char* Bb = Ab + 8192; \
    _Pragma("unroll") \
    for (int r = 0; r < 2; ++r){ \
      int cid = tid + r*256; \
      int rw = cid >> 2, ch = cid & 3; \
      int sc = ch ^ ((rw >> 1) & 3); \
      glds16(Ag + (size_t)rw*768 + (kt)*32 + sc*8, Ab + cid*16 - lane*16); \
      glds16(Bg + (size_t)rw*768 + (kt)*32 + sc*8, Bb + cid*16 - lane*16); \
    } }

  STAGE_K(0, 0);
  __syncthreads();
  const int c0 = lane >> 4;            // k-chunk selector
  for (int kt = 0; kt < 24; ++kt){
    if (kt < 23) STAGE_K((kt+1)&1, kt+1);     // prefetch overlaps compute below
    unsigned char* Ab = smem + (kt&1)*16384;
    unsigned char* Bb = Ab + 8192;
    short8_t af[4], bf[4];
    #pragma unroll
    for (int mf = 0; mf < 4; ++mf){
      int row = wm*64 + mf*16 + (lane & 15);
      int off = row*64 + ((c0 ^ ((row>>1)&3)) << 4);
      af[mf] = *(const short8_t*)(Ab + off);
    }
    #pragma unroll
    for (int nf = 0; nf < 4; ++nf){
      int row = wn*64 + nf*16 + (lane & 15);
      int off = row*64 + ((c0 ^ ((row>>1)&3)) << 4);
      bf[nf] = *(const short8_t*)(Bb + off);
    }
    #pragma unroll
    for (int mf = 0; mf < 4; ++mf){
      #pragma unroll
      for (int nf = 0; nf < 4; ++nf)
        acc[mf][nf] = __builtin_amdgcn_mfma_f32_16x16x32_bf16(af[mf], bf[nf], acc[mf][nf], 0, 0, 0);
    }
    __syncthreads();   // single drain per step
  }
  #undef STAGE_K

  // ---- epilogue: D -> swizzled LDS (aliases bufs) -> contiguous 32 KB store ----
  unsigned char* Ds = smem;              // 32 KB: [q_local 128][bc_local 128] bf16
  #pragma unroll
  for (int mf = 0; mf < 4; ++mf){
    int bc = wm*64 + mf*16 + ((lane >> 4) << 2);
    #pragma unroll
    for (int nf = 0; nf < 4; ++nf){
      int q = wn*64 + nf*16 + (lane & 15);
      f32x4 a = acc[mf][nf];
      ushort4 o;
      o.x = f2bf(a[0]); o.y = f2bf(a[1]); o.z = f2bf(a[2]); o.w = f2bf(a[3]);
      int off = q*256 + bc*2; off ^= (q & 7) << 4;
      *(ushort4*)(Ds + off) = o;
    }
  }
  __syncthreads();
  unsigned short* Yb = Y + ((size_t)(h*32 + bx)*768 + by*128)*128;
  #pragma unroll
  for (int it = 0; it < 8; ++it){
    int fl = it*256 + tid;
    int q = fl >> 4, chunk = fl & 15;
    int off = q*256 + chunk*16; off ^= (q & 7) << 4;
    uint4 val = *(const uint4*)(Ds + off);
    *(uint4*)(Yb + (size_t)fl*8) = val;
  }
}

// ------- K5: out[b][q][:] = (y*gate) @ wout^T via MFMA (hi/lo split) -------
__global__ __launch_bounds__(256) void k_final(
    const unsigned short* __restrict__ Y, const unsigned short* __restrict__ gate,
    const unsigned short* __restrict__ WoH, const unsigned short* __restrict__ WoL,
    float* __restrict__ out)
{
  const int p = blockIdx.x;
  const int r = p & 7, t = p >> 3;
  const int b  = r*64 + (t & 63);
  const int q0 = (t >> 6) * 64;
  const int tid = threadIdx.x, w = tid >> 6, lane = tid & 63;
  const int lr = lane & 15, lc = lane >> 4;

  short8_t bh[4][2], bl[4][2];
  #pragma unroll
  for (int nf = 0; nf < 4; ++nf){
    #pragma unroll
    for (int s = 0; s < 2; ++s){
      bh[nf][s] = *(const short8_t*)(WoH + (nf*16 + lr)*64 + s*32 + lc*8);
      bl[nf][s] = *(const short8_t*)(WoL + (nf*16 + lr)*64 + s*32 + lc*8);
    }
  }

  const int q = q0 + w*16 + lr;
  short8_t ah[2], al[2];
  #pragma unroll
  for (int s = 0; s < 2; ++s){
    const int hh = s*4 + lc;          // head = i>>3
    short8_t y8 = *(const short8_t*)(Y + ((size_t)(hh*32 + (b >> 4))*768 + q)*128 + (b & 15)*8);
    short8_t g8 = *(const short8_t*)(gate + ((size_t)b*NRES + q)*MSAC + s*32 + lc*8);
    #pragma unroll
    for (int e = 0; e < 8; ++e){
      float pp = bf2f((unsigned short)y8[e]) * bf2f((unsigned short)g8[e]);
      unsigned short hi = f2bf(pp);
      ah[s][e] = (short)hi;
      al[s][e] = (short)f2bf(pp - bf2f(hi));
    }
  }

  f32x4 acc[4];
  #pragma unroll
  for (int nf = 0; nf < 4; ++nf) acc[nf] = 0.f;
  #pragma unroll
  for (int nf = 0; nf < 4; ++nf){
    #pragma unroll
    for (int s = 0; s < 2; ++s){
      acc[nf] = __builtin_amdgcn_mfma_f32_16x16x32_bf16(ah[s], bh[nf][s], acc[nf], 0, 0, 0);
      acc[nf] = __builtin_amdgcn_mfma_f32_16x16x32_bf16(al[s], bh[nf][s], acc[nf], 0, 0, 0);
      acc[nf] = __builtin_amdgcn_mfma_f32_16x16x32_bf16(ah[s], bl[nf][s], acc[nf], 0, 0, 0);
    }
  }

  #pragma unroll
  for (int nf = 0; nf < 4; ++nf){
    #pragma unroll
    for (int e = 0; e < 4; ++e){
      int qq = q0 + w*16 + lc*4 + e;
      out[((size_t)b*NRES + qq)*MSAC + nf*16 + lr] = acc[nf][e];
    }
  }
}

extern "C" void kernel_launch(void* const* d_in, const int* in_sizes, int n_in,
                              void* d_out, int out_size, void* d_ws, size_t ws_size,
                              hipStream_t stream) {
  (void)in_sizes; (void)n_in; (void)out_size; (void)ws_size;
  const float* act    = (const float*)d_in[0];
  const float* mask   = (const float*)d_in[1];
  const float* pair   = (const float*)d_in[2];
  const float* ascale = (const float*)d_in[3];
  const float* abias  = (const float*)d_in[4];
  const float* pscale = (const float*)d_in[5];
  const float* pbias  = (const float*)d_in[6];
  const float* wl     = (const float*)d_in[7];
  const float* vproj  = (const float*)d_in[8];
  const float* wgate  = (const float*)d_in[9];
  const float* wout   = (const float*)d_in[10];
  float* out = (float*)d_out;

  char* ws = (char*)d_ws;
  float*          mbias   = (float*)(ws);                                   // 3 KB
  unsigned short* WvT     = (unsigned short*)(ws + 4096);                   // 8 KB
  unsigned short* WgT     = (unsigned short*)(ws + 12288);                  // 8 KB
  unsigned short* WoH     = (unsigned short*)(ws + 20480);                  // 8 KB
  unsigned short* WoL     = (unsigned short*)(ws + 28672);                  // 8 KB
  unsigned short* WST     = (unsigned short*)(ws + 36864);                  // 4 KB
  float*          AB      = (float*)(ws + 40960);                           // 64 B
  unsigned short* weights = (unsigned short*)(ws + 45056);                  // 9.4 MB  [h][q][k]
  unsigned short* v       = (unsigned short*)(ws + 45056 + 9437184);        // 50.3 MB [h][bc][k]
  unsigned short* gate    = (unsigned short*)(ws + 45056 + 9437184 + 50331648);       // 50.3 MB [b][k][64]
  unsigned short* y       = (unsigned short*)(ws + 45056 + 9437184 + 2*50331648ull);  // 50.3 MB [h][bx][q][cl]
  float*          logits  = (float*)(ws + 45056 + 9437184 + 3*50331648ull);           // 18.9 MB [q][h][k]

  k_prep2<<<dim3(29), dim3(256), 0, stream>>>(mask, vproj, wgate, wout,
                                              pscale, pbias, wl,
                                              mbias, WvT, WgT, WoH, WoL, WST, AB);
  k_pair<<<dim3(3072), dim3(256), 0, stream>>>(pair, WST, AB, logits);
  k_soft<<<dim3(768), dim3(256), 0, stream>>>(logits, mbias, weights);
  k_act<<<dim3(3072), dim3(512), 0, stream>>>(act, ascale, abias, WvT, WgT, v, gate);
  k_wavg<<<dim3(1536), dim3(256), 0, stream>>>(v, weights, y);
  k_final<<<dim3(6144), dim3(256), 0, stream>>>(y, gate, WoH, WoL, out);
}

// Round 16
// 313.238 us; speedup vs baseline: 1.8621x; 1.0136x over previous
//
#include <hip/hip_runtime.h>
#include <hip/hip_bf16.h>

#define NSEQ 512
#define NRES 768
#define MSAC 64
#define PAIRC 128
#define NHEAD 8

typedef __attribute__((ext_vector_type(8))) short short8_t;
typedef __attribute__((ext_vector_type(4))) float f32x4;

__device__ __forceinline__ float bf2f(unsigned short u){
  return __uint_as_float(((unsigned int)u) << 16);
}
__device__ __forceinline__ unsigned short f2bf(float f){
  unsigned int x = __float_as_uint(f);
  x += 0x7fffu + ((x >> 16) & 1u);   // RTNE
  return (unsigned short)(x >> 16);
}
// async global->LDS, 16B per lane; lds base wave-uniform (HW adds lane*16)
__device__ __forceinline__ void glds16(const void* g, void* l){
  __builtin_amdgcn_global_load_lds(
      (const __attribute__((address_space(1))) unsigned int*)g,
      (__attribute__((address_space(3))) unsigned int*)l, 16, 0, 0);
}

// -------- K0: mask max + weight prep (WvT/WgT/WoH/WoL + WST/AB for pair) --------
__global__ __launch_bounds__(256) void k_prep2(
    const float* __restrict__ mask, const float* __restrict__ vproj,
    const float* __restrict__ wgate, const float* __restrict__ wout,
    const float* __restrict__ pscale, const float* __restrict__ pbias,
    const float* __restrict__ wl,
    float* __restrict__ bias, unsigned short* __restrict__ WvT,
    unsigned short* __restrict__ WgT, unsigned short* __restrict__ WoH,
    unsigned short* __restrict__ WoL, unsigned short* __restrict__ WST,
    float* __restrict__ AB)
{
  const int bid = blockIdx.x, tid = threadIdx.x;
  if (bid < 12){
    __shared__ float red[4][64];
    const int kk = bid*64 + (tid & 63);
    const int bs = tid >> 6;
    float m = -1e30f;
    for (int b = bs; b < NSEQ; b += 4) m = fmaxf(m, mask[(size_t)b*NRES + kk]);
    red[bs][tid & 63] = m;
    __syncthreads();
    if (tid < 64){
      float mm = fmaxf(fmaxf(red[0][tid], red[1][tid]),
                       fmaxf(red[2][tid], red[3][tid]));
      bias[bid*64 + tid] = 1e9f * (bf2f(f2bf(mm)) - 1.0f);  // ref casts max to bf16
    }
  } else if (bid < 28){
    const int t = (bid - 12)*256 + tid;   // 4096 total
    const int j = t >> 6, i = t & 63;
    WvT[t] = f2bf(vproj[i*64 + j]);
    WgT[t] = f2bf(wgate[t]);
    float wv = wout[t];
    unsigned short hh = f2bf(wv);
    WoH[t] = hh;
    WoL[t] = f2bf(wv - bf2f(hh));
  } else {
    #pragma unroll
    for (int i = 0; i < 4; ++i){
      int t = i*256 + tid;              // 1024 entries
      int h = t >> 7, c = t & 127;
      float w = pscale[c] * wl[h*PAIRC + c];
      unsigned short hh = f2bf(w);
      WST[h*PAIRC + c] = hh;
      WST[(h + 8)*PAIRC + c] = f2bf(w - bf2f(hh));
    }
    const int h = tid >> 5, cc = tid & 31;
    float pa = 0.f, pb = 0.f;
    for (int c = cc; c < PAIRC; c += 32){
      float w = wl[h*PAIRC + c];
      pa += pscale[c]*w;  pb += pbias[c]*w;
    }
    #pragma unroll
    for (int m = 1; m < 32; m <<= 1){
      pa += __shfl_xor(pa, m, 64);
      pb += __shfl_xor(pb, m, 64);
    }
    if (cc == 0){ AB[h] = pa; AB[8 + h] = pb; }
  }
}

// ------- K1: merged independent stages: split-K pair logits + act v/gate -------
// bid < 3072: pair role (q = bid>>2, k-quarter = bid&3), zero LDS, no barrier.
// bid >= 3072: act role, abid = bid-3072: b = abid/12, 64-row chunk (abid%12)*64.
// Both roles co-resident -> pair's HBM streaming overlaps act's compute/stores.
__global__ __launch_bounds__(256) void k_pairact(
    const float* __restrict__ pair, const unsigned short* __restrict__ WST,
    const float* __restrict__ AB, float* __restrict__ logits,
    const float* __restrict__ act, const float* __restrict__ ascale,
    const float* __restrict__ abias, const unsigned short* __restrict__ WvT,
    const unsigned short* __restrict__ WgT, unsigned short* __restrict__ v,
    unsigned short* __restrict__ gate)
{
  __shared__ __align__(16) unsigned char sm[18432];   // act role: vt+gt union
  const int bid = blockIdx.x;
  const int tid = threadIdx.x;

  if (bid < 3072){
    // =================== pair role (R15 split-K body) ===================
    const int q = bid >> 2;
    const int quarter = bid & 3;
    const int wv = tid >> 6, lane = tid & 63;
    const int lr = lane & 15, lcq = lane >> 4;

    short8_t wfrag[4];
    #pragma unroll
    for (int s = 0; s < 4; ++s)
      wfrag[s] = *(const short8_t*)(WST + lr*PAIRC + lcq*8 + s*32);

    const int hb = (lcq & 1) * 4;
    float A4[4], B4[4];
    #pragma unroll
    for (int r = 0; r < 4; ++r){ A4[r] = AB[hb + r]; B4[r] = AB[8 + hb + r]; }

    #pragma unroll
    for (int i = 0; i < 3; ++i){
      const int tile = quarter*12 + wv + 4*i;
      const int k0 = tile * 16;
      const float* base = pair + ((size_t)q*NRES + k0 + lr)*PAIRC + lcq*8;
      f32x4 a1 = 0.f, a2 = 0.f;
      float s = 0.f, ss = 0.f;
      #pragma unroll
      for (int st = 0; st < 4; ++st){
        float4 u0 = *(const float4*)(base + st*32);
        float4 u1 = *(const float4*)(base + st*32 + 4);
        float xv[8] = {u0.x,u0.y,u0.z,u0.w,u1.x,u1.y,u1.z,u1.w};
        short8_t xh, xl;
        #pragma unroll
        for (int e = 0; e < 8; ++e){
          s += xv[e]; ss += xv[e]*xv[e];
          unsigned short hi = f2bf(xv[e]);
          xh[e] = (short)hi;
          xl[e] = (short)f2bf(xv[e] - bf2f(hi));
        }
        a1 = __builtin_amdgcn_mfma_f32_16x16x32_bf16(wfrag[st], xh, a1, 0, 0, 0);
        a2 = __builtin_amdgcn_mfma_f32_16x16x32_bf16(wfrag[st], xl, a2, 0, 0, 0);
      }
      s  += __shfl_xor(s, 16, 64);  ss += __shfl_xor(ss, 16, 64);
      s  += __shfl_xor(s, 32, 64);  ss += __shfl_xor(ss, 32, 64);
      const float mu  = s * (1.f/128.f);
      const float var = ss * (1.f/128.f) - mu*mu;
      const float rsq = rsqrtf(var + 1e-5f);
      float d[4];
      #pragma unroll
      for (int r = 0; r < 4; ++r)
        d[r] = a1[r] + __shfl_xor(a1[r], 32, 64) + a2[r];
      if (lane < 32){
        const int k = k0 + lr;
        #pragma unroll
        for (int r = 0; r < 4; ++r)
          logits[(size_t)q*6144 + (hb + r)*768 + k] = rsq * (d[r] - mu * A4[r]) + B4[r];
      }
    }
  } else {
    // =================== act role (R8-proven 256-thr 64-row body) ===================
    unsigned short (*vt)[72] = (unsigned short (*)[72])sm;            // 9216 B
    unsigned short (*gt)[72] = (unsigned short (*)[72])(sm + 9216);   // 9216 B
    const int abid = bid - 3072;
    const int b  = abid / 12;
    const int k0 = (abid % 12) * 64;
    const int w = tid >> 6, lane = tid & 63;
    const int lr = lane & 15;
    const int lc = lane >> 4;
    const int row = k0 + w*16 + lr;

    short8_t bv[4][2], bg[4][2];
    #pragma unroll
    for (int mf = 0; mf < 4; ++mf){
      #pragma unroll
      for (int s = 0; s < 2; ++s){
        bv[mf][s] = *(const short8_t*)(WvT + (mf*16 + lr)*64 + s*32 + lc*8);
        bg[mf][s] = *(const short8_t*)(WgT + (mf*16 + lr)*64 + s*32 + lc*8);
      }
    }

    const float* arow = act + ((size_t)b*NRES + row)*MSAC;
    float x[2][8];
    #pragma unroll
    for (int s = 0; s < 2; ++s){
      float4 t0 = *(const float4*)(arow + s*32 + lc*8);
      float4 t1 = *(const float4*)(arow + s*32 + lc*8 + 4);
      x[s][0]=t0.x; x[s][1]=t0.y; x[s][2]=t0.z; x[s][3]=t0.w;
      x[s][4]=t1.x; x[s][5]=t1.y; x[s][6]=t1.z; x[s][7]=t1.w;
    }
    float ps = 0.f, pss = 0.f;
    #pragma unroll
    for (int s = 0; s < 2; ++s)
      #pragma unroll
      for (int e = 0; e < 8; ++e){ ps += x[s][e]; pss += x[s][e]*x[s][e]; }
    ps  += __shfl_xor(ps, 16, 64);  pss += __shfl_xor(pss, 16, 64);
    ps  += __shfl_xor(ps, 32, 64);  pss += __shfl_xor(pss, 32, 64);
    const float mu  = ps * (1.f/64.f);
    const float var = pss * (1.f/64.f) - mu*mu;
    const float rs  = rsqrtf(var + 1e-5f);

    short8_t a[2];
    #pragma unroll
    for (int s = 0; s < 2; ++s){
      float4 s0 = *(const float4*)(ascale + s*32 + lc*8);
      float4 s1 = *(const float4*)(ascale + s*32 + lc*8 + 4);
      float4 b0 = *(const float4*)(abias  + s*32 + lc*8);
      float4 b1 = *(const float4*)(abias  + s*32 + lc*8 + 4);
      const float sc[8] = {s0.x,s0.y,s0.z,s0.w,s1.x,s1.y,s1.z,s1.w};
      const float bs[8] = {b0.x,b0.y,b0.z,b0.w,b1.x,b1.y,b1.z,b1.w};
      #pragma unroll
      for (int e = 0; e < 8; ++e)
        a[s][e] = (short)f2bf((x[s][e] - mu)*rs*sc[e] + bs[e]);
    }

    f32x4 accv[4], accg[4];
    #pragma unroll
    for (int mf = 0; mf < 4; ++mf){ accv[mf] = 0.f; accg[mf] = 0.f; }
    #pragma unroll
    for (int mf = 0; mf < 4; ++mf){
      #pragma unroll
      for (int s = 0; s < 2; ++s){
        accv[mf] = __builtin_amdgcn_mfma_f32_16x16x32_bf16(a[s], bv[mf][s], accv[mf], 0, 0, 0);
        accg[mf] = __builtin_amdgcn_mfma_f32_16x16x32_bf16(bg[mf][s], a[s], accg[mf], 0, 0, 0);
      }
    }

    #pragma unroll
    for (int mf = 0; mf < 4; ++mf){
      ushort4 ov;
      ov.x = f2bf(accv[mf][0]); ov.y = f2bf(accv[mf][1]);
      ov.z = f2bf(accv[mf][2]); ov.w = f2bf(accv[mf][3]);
      *(ushort4*)&vt[mf*16 + lr][w*16 + lc*4] = ov;
      ushort4 og;
      og.x = f2bf(1.0f/(1.0f + __expf(-accg[mf][0])));
      og.y = f2bf(1.0f/(1.0f + __expf(-accg[mf][1])));
      og.z = f2bf(1.0f/(1.0f + __expf(-accg[mf][2])));
      og.w = f2bf(1.0f/(1.0f + __expf(-accg[mf][3])));
      *(ushort4*)&gt[w*16 + lr][mf*16 + lc*4] = og;
    }
    __syncthreads();
    #pragma unroll
    for (int it = 0; it < 2; ++it){
      int fl = it*256 + tid;
      int j = fl >> 3, chunk = fl & 7;
      uint4 val = *(const uint4*)&vt[j][chunk*8];
      *(uint4*)(v + ((size_t)(j >> 3)*4096 + (size_t)b*8 + (j & 7))*NRES + k0 + chunk*8) = val;
    }
    #pragma unroll
    for (int it = 0; it < 2; ++it){
      int fl = it*256 + tid;
      int k = fl >> 3, chunk = fl & 7;
      uint4 val = *(const uint4*)&gt[k][chunk*8];
      *(uint4*)(gate + ((size_t)b*NRES + k0 + k)*MSAC + chunk*8) = val;
    }
  }
}

// ------- K1s: softmax over k: logits[q][h][k] + mbias -> weights bf16 [h][q][k] -------
__global__ __launch_bounds__(256) void k_soft(
    const float* __restrict__ logits, const float* __restrict__ mbias,
    unsigned short* __restrict__ weights)
{
  __shared__ float lgf[6144];   // 24 KB: [h][k] for this q
  const int q = blockIdx.x, tid = threadIdx.x;
  const float* src = logits + (size_t)q*6144;
  #pragma unroll
  for (int i = 0; i < 6; ++i){
    int idx = (i*256 + tid)*4;
    *(float4*)&lgf[idx] = *(const float4*)(src + idx);
  }
  __syncthreads();
  const int wv = tid >> 6, lane = tid & 63;
  #pragma unroll
  for (int hh = 0; hh < 2; ++hh){
    int h = wv + hh*4;
    float mx = -1e30f;
    for (int kk = lane; kk < NRES; kk += 64) mx = fmaxf(mx, lgf[h*768 + kk] + mbias[kk]);
    #pragma unroll
    for (int m = 1; m < 64; m <<= 1) mx = fmaxf(mx, __shfl_xor(mx, m, 64));
    float sum = 0.f;
    for (int kk = lane; kk < NRES; kk += 64){
      float e = __expf(lgf[h*768 + kk] + mbias[kk] - mx);
      lgf[h*768 + kk] = e; sum += e;
    }
    #pragma unroll
    for (int m = 1; m < 64; m <<= 1) sum += __shfl_xor(sum, m, 64);
    float inv = 1.0f / sum;
    unsigned short* wrow = weights + ((size_t)h * NRES + q) * NRES;
    for (int kk = lane; kk < NRES; kk += 64) wrow[kk] = f2bf(lgf[h*768 + kk] * inv);
  }
}

// ------- K4: per-head GEMM  Y3[h][bx][q][cl] = weights[h] @ v[h] -------
// 2-phase double-buffered pipeline, BK=32, single barrier per K-step.
__global__ __launch_bounds__(256) void k_wavg(
    const unsigned short* __restrict__ V, const unsigned short* __restrict__ W,
    unsigned short* __restrict__ Y)
{
  __shared__ unsigned char smem[32768];

  const int flat = blockIdx.x;
  const int nid  = (flat & 7) * 192 + (flat >> 3);   // XCD chunk of 192 = 1 head
  const int m    = nid % 192;
  const int by   = m % 6;              // fastest: A-tile reuse across 6 blocks
  const int bx   = m / 6;
  const int h    = nid / 192;

  const int tid = threadIdx.x, wid = tid >> 6, lane = tid & 63;
  const int wm = wid & 1, wn = wid >> 1;
  const unsigned short* Ag = V + (size_t)h*4096*768 + (size_t)bx*128*768;
  const unsigned short* Bg = W + (size_t)h*768*768 + (size_t)by*128*768;

  f32x4 acc[4][4];
  #pragma unroll
  for (int i=0;i<4;++i){
    #pragma unroll
    for (int jj=0;jj<4;++jj) acc[i][jj] = 0.f;
  }

  #define STAGE_K(bufsel, kt) { \
    unsigned char* Ab = smem + (bufsel)*16384; \
    unsigned char* Bb = Ab + 8192; \
    _Pragma("unroll") \
    for (int r = 0; r < 2; ++r){ \
      int cid = tid + r*256; \
      int rw = cid >> 2, ch = cid & 3; \
      int sc = ch ^ ((rw >> 1) & 3); \
      glds16(Ag + (size_t)rw*768 + (kt)*32 + sc*8, Ab + cid*16 - lane*16); \
      glds16(Bg + (size_t)rw*768 + (kt)*32 + sc*8, Bb + cid*16 - lane*16); \
    } }

  STAGE_K(0, 0);
  __syncthreads();
  const int c0 = lane >> 4;            // k-chunk selector
  for (int kt = 0; kt < 24; ++kt){
    if (kt < 23) STAGE_K((kt+1)&1, kt+1);     // prefetch overlaps compute below
    unsigned char* Ab = smem + (kt&1)*16384;
    unsigned char* Bb = Ab + 8192;
    short8_t af[4], bf[4];
    #pragma unroll
    for (int mf = 0; mf < 4; ++mf){
      int row = wm*64 + mf*16 + (lane & 15);
      int off = row*64 + ((c0 ^ ((row>>1)&3)) << 4);
      af[mf] = *(const short8_t*)(Ab + off);
    }
    #pragma unroll
    for (int nf = 0; nf < 4; ++nf){
      int row = wn*64 + nf*16 + (lane & 15);
      int off = row*64 + ((c0 ^ ((row>>1)&3)) << 4);
      bf[nf] = *(const short8_t*)(Bb + off);
    }
    #pragma unroll
    for (int mf = 0; mf < 4; ++mf){
      #pragma unroll
      for (int nf = 0; nf < 4; ++nf)
        acc[mf][nf] = __builtin_amdgcn_mfma_f32_16x16x32_bf16(af[mf], bf[nf], acc[mf][nf], 0, 0, 0);
    }
    __syncthreads();   // single drain per step
  }
  #undef STAGE_K

  // ---- epilogue: D -> swizzled LDS (aliases bufs) -> contiguous 32 KB store ----
  unsigned char* Ds = smem;              // 32 KB: [q_local 128][bc_local 128] bf16
  #pragma unroll
  for (int mf = 0; mf < 4; ++mf){
    int bc = wm*64 + mf*16 + ((lane >> 4) << 2);
    #pragma unroll
    for (int nf = 0; nf < 4; ++nf){
      int q = wn*64 + nf*16 + (lane & 15);
      f32x4 a = acc[mf][nf];
      ushort4 o;
      o.x = f2bf(a[0]); o.y = f2bf(a[1]); o.z = f2bf(a[2]); o.w = f2bf(a[3]);
      int off = q*256 + bc*2; off ^= (q & 7) << 4;
      *(ushort4*)(Ds + off) = o;
    }
  }
  __syncthreads();
  unsigned short* Yb = Y + ((size_t)(h*32 + bx)*768 + by*128)*128;
  #pragma unroll
  for (int it = 0; it < 8; ++it){
    int fl = it*256 + tid;
    int q = fl >> 4, chunk = fl & 15;
    int off = q*256 + chunk*16; off ^= (q & 7) << 4;
    uint4 val = *(const uint4*)(Ds + off);
    *(uint4*)(Yb + (size_t)fl*8) = val;
  }
}

// ------- K5: out[b][q][:] = (y*gate) @ wout^T via MFMA (hi/lo split) -------
__global__ __launch_bounds__(256) void k_final(
    const unsigned short* __restrict__ Y, const unsigned short* __restrict__ gate,
    const unsigned short* __restrict__ WoH, const unsigned short* __restrict__ WoL,
    float* __restrict__ out)
{
  const int p = blockIdx.x;
  const int r = p & 7, t = p >> 3;
  const int b  = r*64 + (t & 63);
  const int q0 = (t >> 6) * 64;
  const int tid = threadIdx.x, w = tid >> 6, lane = tid & 63;
  const int lr = lane & 15, lc = lane >> 4;

  short8_t bh[4][2], bl[4][2];
  #pragma unroll
  for (int nf = 0; nf < 4; ++nf){
    #pragma unroll
    for (int s = 0; s < 2; ++s){
      bh[nf][s] = *(const short8_t*)(WoH + (nf*16 + lr)*64 + s*32 + lc*8);
      bl[nf][s] = *(const short8_t*)(WoL + (nf*16 + lr)*64 + s*32 + lc*8);
    }
  }

  const int q = q0 + w*16 + lr;
  short8_t ah[2], al[2];
  #pragma unroll
  for (int s = 0; s < 2; ++s){
    const int hh = s*4 + lc;          // head = i>>3
    short8_t y8 = *(const short8_t*)(Y + ((size_t)(hh*32 + (b >> 4))*768 + q)*128 + (b & 15)*8);
    short8_t g8 = *(const short8_t*)(gate + ((size_t)b*NRES + q)*MSAC + s*32 + lc*8);
    #pragma unroll
    for (int e = 0; e < 8; ++e){
      float pp = bf2f((unsigned short)y8[e]) * bf2f((unsigned short)g8[e]);
      unsigned short hi = f2bf(pp);
      ah[s][e] = (short)hi;
      al[s][e] = (short)f2bf(pp - bf2f(hi));
    }
  }

  f32x4 acc[4];
  #pragma unroll
  for (int nf = 0; nf < 4; ++nf) acc[nf] = 0.f;
  #pragma unroll
  for (int nf = 0; nf < 4; ++nf){
    #pragma unroll
    for (int s = 0; s < 2; ++s){
      acc[nf] = __builtin_amdgcn_mfma_f32_16x16x32_bf16(ah[s], bh[nf][s], acc[nf], 0, 0, 0);
      acc[nf] = __builtin_amdgcn_mfma_f32_16x16x32_bf16(al[s], bh[nf][s], acc[nf], 0, 0, 0);
      acc[nf] = __builtin_amdgcn_mfma_f32_16x16x32_bf16(ah[s], bl[nf][s], acc[nf], 0, 0, 0);
    }
  }

  #pragma unroll
  for (int nf = 0; nf < 4; ++nf){
    #pragma unroll
    for (int e = 0; e < 4; ++e){
      int qq = q0 + w*16 + lc*4 + e;
      out[((size_t)b*NRES + qq)*MSAC + nf*16 + lr] = acc[nf][e];
    }
  }
}

extern "C" void kernel_launch(void* const* d_in, const int* in_sizes, int n_in,
                              void* d_out, int out_size, void* d_ws, size_t ws_size,
                              hipStream_t stream) {
  (void)in_sizes; (void)n_in; (void)out_size; (void)ws_size;
  const float* act    = (const float*)d_in[0];
  const float* mask   = (const float*)d_in[1];
  const float* pair   = (const float*)d_in[2];
  const float* ascale = (const float*)d_in[3];
  const float* abias  = (const float*)d_in[4];
  const float* pscale = (const float*)d_in[5];
  const float* pbias  = (const float*)d_in[6];
  const float* wl     = (const float*)d_in[7];
  const float* vproj  = (const float*)d_in[8];
  const float* wgate  = (const float*)d_in[9];
  const float* wout   = (const float*)d_in[10];
  float* out = (float*)d_out;

  char* ws = (char*)d_ws;
  float*          mbias   = (float*)(ws);                                   // 3 KB
  unsigned short* WvT     = (unsigned short*)(ws + 4096);                   // 8 KB
  unsigned short* WgT     = (unsigned short*)(ws + 12288);                  // 8 KB
  unsigned short* WoH     = (unsigned short*)(ws + 20480);                  // 8 KB
  unsigned short* WoL     = (unsigned short*)(ws + 28672);                  // 8 KB
  unsigned short* WST     = (unsigned short*)(ws + 36864);                  // 4 KB
  float*          AB      = (float*)(ws + 40960);                           // 64 B
  unsigned short* weights = (unsigned short*)(ws + 45056);                  // 9.4 MB  [h][q][k]
  unsigned short* v       = (unsigned short*)(ws + 45056 + 9437184);        // 50.3 MB [h][bc][k]
  unsigned short* gate    = (unsigned short*)(ws + 45056 + 9437184 + 50331648);       // 50.3 MB [b][k][64]
  unsigned short* y       = (unsigned short*)(ws + 45056 + 9437184 + 2*50331648ull);  // 50.3 MB [h][bx][q][cl]
  float*          logits  = (float*)(ws + 45056 + 9437184 + 3*50331648ull);           // 18.9 MB [q][h][k]

  k_prep2<<<dim3(29), dim3(256), 0, stream>>>(mask, vproj, wgate, wout,
                                              pscale, pbias, wl,
                                              mbias, WvT, WgT, WoH, WoL, WST, AB);
  k_pairact<<<dim3(9216), dim3(256), 0, stream>>>(pair, WST, AB, logits,
                                                  act, ascale, abias, WvT, WgT, v, gate);
  k_soft<<<dim3(768), dim3(256), 0, stream>>>(logits, mbias, weights);
  k_wavg<<<dim3(1536), dim3(256), 0, stream>>>(v, weights, y);
  k_final<<<dim3(6144), dim3(256), 0, stream>>>(y, gate, WoH, WoL, out);
}

// Round 17
// 303.899 us; speedup vs baseline: 1.9193x; 1.0307x over previous
//
#include <hip/hip_runtime.h>
#include <hip/hip_bf16.h>

#define NSEQ 512
#define NRES 768
#define MSAC 64
#define PAIRC 128
#define NHEAD 8

typedef __attribute__((ext_vector_type(8))) short short8_t;
typedef __attribute__((ext_vector_type(4))) float f32x4;

__device__ __forceinline__ float bf2f(unsigned short u){
  return __uint_as_float(((unsigned int)u) << 16);
}
__device__ __forceinline__ unsigned short f2bf(float f){
  unsigned int x = __float_as_uint(f);
  x += 0x7fffu + ((x >> 16) & 1u);   // RTNE
  return (unsigned short)(x >> 16);
}
// async global->LDS, 16B per lane; lds base wave-uniform (HW adds lane*16)
__device__ __forceinline__ void glds16(const void* g, void* l){
  __builtin_amdgcn_global_load_lds(
      (const __attribute__((address_space(1))) unsigned int*)g,
      (__attribute__((address_space(3))) unsigned int*)l, 16, 0, 0);
}

// -------- K0: mask max + weight prep (WvT/WgT/WoH/WoL + WST/AB for pair) --------
__global__ __launch_bounds__(256) void k_prep2(
    const float* __restrict__ mask, const float* __restrict__ vproj,
    const float* __restrict__ wgate, const float* __restrict__ wout,
    const float* __restrict__ pscale, const float* __restrict__ pbias,
    const float* __restrict__ wl,
    float* __restrict__ bias, unsigned short* __restrict__ WvT,
    unsigned short* __restrict__ WgT, unsigned short* __restrict__ WoH,
    unsigned short* __restrict__ WoL, unsigned short* __restrict__ WST,
    float* __restrict__ AB)
{
  const int bid = blockIdx.x, tid = threadIdx.x;
  if (bid < 12){
    __shared__ float red[4][64];
    const int kk = bid*64 + (tid & 63);
    const int bs = tid >> 6;
    float m = -1e30f;
    for (int b = bs; b < NSEQ; b += 4) m = fmaxf(m, mask[(size_t)b*NRES + kk]);
    red[bs][tid & 63] = m;
    __syncthreads();
    if (tid < 64){
      float mm = fmaxf(fmaxf(red[0][tid], red[1][tid]),
                       fmaxf(red[2][tid], red[3][tid]));
      bias[bid*64 + tid] = 1e9f * (bf2f(f2bf(mm)) - 1.0f);  // ref casts max to bf16
    }
  } else if (bid < 28){
    const int t = (bid - 12)*256 + tid;   // 4096 total
    const int j = t >> 6, i = t & 63;
    WvT[t] = f2bf(vproj[i*64 + j]);
    WgT[t] = f2bf(wgate[t]);
    float wv = wout[t];
    unsigned short hh = f2bf(wv);
    WoH[t] = hh;
    WoL[t] = f2bf(wv - bf2f(hh));
  } else {
    #pragma unroll
    for (int i = 0; i < 4; ++i){
      int t = i*256 + tid;              // 1024 entries
      int h = t >> 7, c = t & 127;
      float w = pscale[c] * wl[h*PAIRC + c];
      unsigned short hh = f2bf(w);
      WST[h*PAIRC + c] = hh;
      WST[(h + 8)*PAIRC + c] = f2bf(w - bf2f(hh));
    }
    const int h = tid >> 5, cc = tid & 31;
    float pa = 0.f, pb = 0.f;
    for (int c = cc; c < PAIRC; c += 32){
      float w = wl[h*PAIRC + c];
      pa += pscale[c]*w;  pb += pbias[c]*w;
    }
    #pragma unroll
    for (int m = 1; m < 32; m <<= 1){
      pa += __shfl_xor(pa, m, 64);
      pb += __shfl_xor(pb, m, 64);
    }
    if (cc == 0){ AB[h] = pa; AB[8 + h] = pb; }
  }
}

// ------- K1: merged pair + act, roles INTERLEAVED in dispatch order -------
// bid % 3 == 0 -> pair role (pid = bid/3: q = pid>>2, quarter = pid&3)
// else         -> act role  (aid = 2*(bid/3) + (bid%3 - 1): b = aid/12, chunk)
// Interleaving gives true co-residency: pair's HBM streaming overlaps act's
// MFMA/stores on every CU (R16's bid<3072 split serialized the roles).
__global__ __launch_bounds__(256) void k_pairact(
    const float* __restrict__ pair, const unsigned short* __restrict__ WST,
    const float* __restrict__ AB, float* __restrict__ logits,
    const float* __restrict__ act, const float* __restrict__ ascale,
    const float* __restrict__ abias, const unsigned short* __restrict__ WvT,
    const unsigned short* __restrict__ WgT, unsigned short* __restrict__ v,
    unsigned short* __restrict__ gate)
{
  __shared__ __align__(16) unsigned char sm[18432];   // act role: vt+gt union
  const int bid = blockIdx.x;
  const int tid = threadIdx.x;
  const int g3 = bid / 3, r3 = bid % 3;

  if (r3 == 0){
    // =================== pair role (split-K body) ===================
    const int pid = g3;
    const int q = pid >> 2;
    const int quarter = pid & 3;
    const int wv = tid >> 6, lane = tid & 63;
    const int lr = lane & 15, lcq = lane >> 4;

    short8_t wfrag[4];
    #pragma unroll
    for (int s = 0; s < 4; ++s)
      wfrag[s] = *(const short8_t*)(WST + lr*PAIRC + lcq*8 + s*32);

    const int hb = (lcq & 1) * 4;
    float A4[4], B4[4];
    #pragma unroll
    for (int r = 0; r < 4; ++r){ A4[r] = AB[hb + r]; B4[r] = AB[8 + hb + r]; }

    #pragma unroll
    for (int i = 0; i < 3; ++i){
      const int tile = quarter*12 + wv + 4*i;
      const int k0 = tile * 16;
      const float* base = pair + ((size_t)q*NRES + k0 + lr)*PAIRC + lcq*8;
      f32x4 a1 = 0.f, a2 = 0.f;
      float s = 0.f, ss = 0.f;
      #pragma unroll
      for (int st = 0; st < 4; ++st){
        float4 u0 = *(const float4*)(base + st*32);
        float4 u1 = *(const float4*)(base + st*32 + 4);
        float xv[8] = {u0.x,u0.y,u0.z,u0.w,u1.x,u1.y,u1.z,u1.w};
        short8_t xh, xl;
        #pragma unroll
        for (int e = 0; e < 8; ++e){
          s += xv[e]; ss += xv[e]*xv[e];
          unsigned short hi = f2bf(xv[e]);
          xh[e] = (short)hi;
          xl[e] = (short)f2bf(xv[e] - bf2f(hi));
        }
        a1 = __builtin_amdgcn_mfma_f32_16x16x32_bf16(wfrag[st], xh, a1, 0, 0, 0);
        a2 = __builtin_amdgcn_mfma_f32_16x16x32_bf16(wfrag[st], xl, a2, 0, 0, 0);
      }
      s  += __shfl_xor(s, 16, 64);  ss += __shfl_xor(ss, 16, 64);
      s  += __shfl_xor(s, 32, 64);  ss += __shfl_xor(ss, 32, 64);
      const float mu  = s * (1.f/128.f);
      const float var = ss * (1.f/128.f) - mu*mu;
      const float rsq = rsqrtf(var + 1e-5f);
      float d[4];
      #pragma unroll
      for (int r = 0; r < 4; ++r)
        d[r] = a1[r] + __shfl_xor(a1[r], 32, 64) + a2[r];
      if (lane < 32){
        const int k = k0 + lr;
        #pragma unroll
        for (int r = 0; r < 4; ++r)
          logits[(size_t)q*6144 + (hb + r)*768 + k] = rsq * (d[r] - mu * A4[r]) + B4[r];
      }
    }
  } else {
    // =================== act role (R8-proven 256-thr 64-row body) ===================
    unsigned short (*vt)[72] = (unsigned short (*)[72])sm;            // 9216 B
    unsigned short (*gt)[72] = (unsigned short (*)[72])(sm + 9216);   // 9216 B
    const int aid = 2*g3 + (r3 - 1);
    const int b  = aid / 12;
    const int k0 = (aid % 12) * 64;
    const int w = tid >> 6, lane = tid & 63;
    const int lr = lane & 15;
    const int lc = lane >> 4;
    const int row = k0 + w*16 + lr;

    short8_t bv[4][2], bg[4][2];
    #pragma unroll
    for (int mf = 0; mf < 4; ++mf){
      #pragma unroll
      for (int s = 0; s < 2; ++s){
        bv[mf][s] = *(const short8_t*)(WvT + (mf*16 + lr)*64 + s*32 + lc*8);
        bg[mf][s] = *(const short8_t*)(WgT + (mf*16 + lr)*64 + s*32 + lc*8);
      }
    }

    const float* arow = act + ((size_t)b*NRES + row)*MSAC;
    float x[2][8];
    #pragma unroll
    for (int s = 0; s < 2; ++s){
      float4 t0 = *(const float4*)(arow + s*32 + lc*8);
      float4 t1 = *(const float4*)(arow + s*32 + lc*8 + 4);
      x[s][0]=t0.x; x[s][1]=t0.y; x[s][2]=t0.z; x[s][3]=t0.w;
      x[s][4]=t1.x; x[s][5]=t1.y; x[s][6]=t1.z; x[s][7]=t1.w;
    }
    float ps = 0.f, pss = 0.f;
    #pragma unroll
    for (int s = 0; s < 2; ++s)
      #pragma unroll
      for (int e = 0; e < 8; ++e){ ps += x[s][e]; pss += x[s][e]*x[s][e]; }
    ps  += __shfl_xor(ps, 16, 64);  pss += __shfl_xor(pss, 16, 64);
    ps  += __shfl_xor(ps, 32, 64);  pss += __shfl_xor(pss, 32, 64);
    const float mu  = ps * (1.f/64.f);
    const float var = pss * (1.f/64.f) - mu*mu;
    const float rs  = rsqrtf(var + 1e-5f);

    short8_t a[2];
    #pragma unroll
    for (int s = 0; s < 2; ++s){
      float4 s0 = *(const float4*)(ascale + s*32 + lc*8);
      float4 s1 = *(const float4*)(ascale + s*32 + lc*8 + 4);
      float4 b0 = *(const float4*)(abias  + s*32 + lc*8);
      float4 b1 = *(const float4*)(abias  + s*32 + lc*8 + 4);
      const float sc[8] = {s0.x,s0.y,s0.z,s0.w,s1.x,s1.y,s1.z,s1.w};
      const float bs[8] = {b0.x,b0.y,b0.z,b0.w,b1.x,b1.y,b1.z,b1.w};
      #pragma unroll
      for (int e = 0; e < 8; ++e)
        a[s][e] = (short)f2bf((x[s][e] - mu)*rs*sc[e] + bs[e]);
    }

    f32x4 accv[4], accg[4];
    #pragma unroll
    for (int mf = 0; mf < 4; ++mf){ accv[mf] = 0.f; accg[mf] = 0.f; }
    #pragma unroll
    for (int mf = 0; mf < 4; ++mf){
      #pragma unroll
      for (int s = 0; s < 2; ++s){
        accv[mf] = __builtin_amdgcn_mfma_f32_16x16x32_bf16(a[s], bv[mf][s], accv[mf], 0, 0, 0);
        accg[mf] = __builtin_amdgcn_mfma_f32_16x16x32_bf16(bg[mf][s], a[s], accg[mf], 0, 0, 0);
      }
    }

    #pragma unroll
    for (int mf = 0; mf < 4; ++mf){
      ushort4 ov;
      ov.x = f2bf(accv[mf][0]); ov.y = f2bf(accv[mf][1]);
      ov.z = f2bf(accv[mf][2]); ov.w = f2bf(accv[mf][3]);
      *(ushort4*)&vt[mf*16 + lr][w*16 + lc*4] = ov;
      ushort4 og;
      og.x = f2bf(1.0f/(1.0f + __expf(-accg[mf][0])));
      og.y = f2bf(1.0f/(1.0f + __expf(-accg[mf][1])));
      og.z = f2bf(1.0f/(1.0f + __expf(-accg[mf][2])));
      og.w = f2bf(1.0f/(1.0f + __expf(-accg[mf][3])));
      *(ushort4*)&gt[w*16 + lr][mf*16 + lc*4] = og;
    }
    __syncthreads();
    #pragma unroll
    for (int it = 0; it < 2; ++it){
      int fl = it*256 + tid;
      int j = fl >> 3, chunk = fl & 7;
      uint4 val = *(const uint4*)&vt[j][chunk*8];
      *(uint4*)(v + ((size_t)(j >> 3)*4096 + (size_t)b*8 + (j & 7))*NRES + k0 + chunk*8) = val;
    }
    #pragma unroll
    for (int it = 0; it < 2; ++it){
      int fl = it*256 + tid;
      int k = fl >> 3, chunk = fl & 7;
      uint4 val = *(const uint4*)&gt[k][chunk*8];
      *(uint4*)(gate + ((size_t)b*NRES + k0 + k)*MSAC + chunk*8) = val;
    }
  }
}

// ------- K1s: softmax over k: logits[q][h][k] + mbias -> weights bf16 [h][q][k] -------
__global__ __launch_bounds__(256) void k_soft(
    const float* __restrict__ logits, const float* __restrict__ mbias,
    unsigned short* __restrict__ weights)
{
  __shared__ float lgf[6144];   // 24 KB: [h][k] for this q
  const int q = blockIdx.x, tid = threadIdx.x;
  const float* src = logits + (size_t)q*6144;
  #pragma unroll
  for (int i = 0; i < 6; ++i){
    int idx = (i*256 + tid)*4;
    *(float4*)&lgf[idx] = *(const float4*)(src + idx);
  }
  __syncthreads();
  const int wv = tid >> 6, lane = tid & 63;
  #pragma unroll
  for (int hh = 0; hh < 2; ++hh){
    int h = wv + hh*4;
    float mx = -1e30f;
    for (int kk = lane; kk < NRES; kk += 64) mx = fmaxf(mx, lgf[h*768 + kk] + mbias[kk]);
    #pragma unroll
    for (int m = 1; m < 64; m <<= 1) mx = fmaxf(mx, __shfl_xor(mx, m, 64));
    float sum = 0.f;
    for (int kk = lane; kk < NRES; kk += 64){
      float e = __expf(lgf[h*768 + kk] + mbias[kk] - mx);
      lgf[h*768 + kk] = e; sum += e;
    }
    #pragma unroll
    for (int m = 1; m < 64; m <<= 1) sum += __shfl_xor(sum, m, 64);
    float inv = 1.0f / sum;
    unsigned short* wrow = weights + ((size_t)h * NRES + q) * NRES;
    for (int kk = lane; kk < NRES; kk += 64) wrow[kk] = f2bf(lgf[h*768 + kk] * inv);
  }
}

// ------- K4: per-head GEMM  Y3[h][bx][q][cl] = weights[h] @ v[h] -------
// 2-phase double-buffered pipeline, BK=32, single barrier per K-step.
__global__ __launch_bounds__(256) void k_wavg(
    const unsigned short* __restrict__ V, const unsigned short* __restrict__ W,
    unsigned short* __restrict__ Y)
{
  __shared__ unsigned char smem[32768];

  const int flat = blockIdx.x;
  const int nid  = (flat & 7) * 192 + (flat >> 3);   // XCD chunk of 192 = 1 head
  const int m    = nid % 192;
  const int by   = m % 6;              // fastest: A-tile reuse across 6 blocks
  const int bx   = m / 6;
  const int h    = nid / 192;

  const int tid = threadIdx.x, wid = tid >> 6, lane = tid & 63;
  const int wm = wid & 1, wn = wid >> 1;
  const unsigned short* Ag = V + (size_t)h*4096*768 + (size_t)bx*128*768;
  const unsigned short* Bg = W + (size_t)h*768*768 + (size_t)by*128*768;

  f32x4 acc[4][4];
  #pragma unroll
  for (int i=0;i<4;++i){
    #pragma unroll
    for (int jj=0;jj<4;++jj) acc[i][jj] = 0.f;
  }

  #define STAGE_K(bufsel, kt) { \
    unsigned char* Ab = smem + (bufsel)*16384; \
    unsigned char* Bb = Ab + 8192; \
    _Pragma("unroll") \
    for (int r = 0; r < 2; ++r){ \
      int cid = tid + r*256; \
      int rw = cid >> 2, ch = cid & 3; \
      int sc = ch ^ ((rw >> 1) & 3); \
      glds16(Ag + (size_t)rw*768 + (kt)*32 + sc*8, Ab + cid*16 - lane*16); \
      glds16(Bg + (size_t)rw*768 + (kt)*32 + sc*8, Bb + cid*16 - lane*16); \
    } }

  STAGE_K(0, 0);
  __syncthreads();
  const int c0 = lane >> 4;            // k-chunk selector
  for (int kt = 0; kt < 24; ++kt){
    if (kt < 23) STAGE_K((kt+1)&1, kt+1);     // prefetch overlaps compute below
    unsigned char* Ab = smem + (kt&1)*16384;
    unsigned char* Bb = Ab + 8192;
    short8_t af[4], bf[4];
    #pragma unroll
    for (int mf = 0; mf < 4; ++mf){
      int row = wm*64 + mf*16 + (lane & 15);
      int off = row*64 + ((c0 ^ ((row>>1)&3)) << 4);
      af[mf] = *(const short8_t*)(Ab + off);
    }
    #pragma unroll
    for (int nf = 0; nf < 4; ++nf){
      int row = wn*64 + nf*16 + (lane & 15);
      int off = row*64 + ((c0 ^ ((row>>1)&3)) << 4);
      bf[nf] = *(const short8_t*)(Bb + off);
    }
    #pragma unroll
    for (int mf = 0; mf < 4; ++mf){
      #pragma unroll
      for (int nf = 0; nf < 4; ++nf)
        acc[mf][nf] = __builtin_amdgcn_mfma_f32_16x16x32_bf16(af[mf], bf[nf], acc[mf][nf], 0, 0, 0);
    }
    __syncthreads();   // single drain per step
  }
  #undef STAGE_K

  // ---- epilogue: D -> swizzled LDS (aliases bufs) -> contiguous 32 KB store ----
  unsigned char* Ds = smem;              // 32 KB: [q_local 128][bc_local 128] bf16
  #pragma unroll
  for (int mf = 0; mf < 4; ++mf){
    int bc = wm*64 + mf*16 + ((lane >> 4) << 2);
    #pragma unroll
    for (int nf = 0; nf < 4; ++nf){
      int q = wn*64 + nf*16 + (lane & 15);
      f32x4 a = acc[mf][nf];
      ushort4 o;
      o.x = f2bf(a[0]); o.y = f2bf(a[1]); o.z = f2bf(a[2]); o.w = f2bf(a[3]);
      int off = q*256 + bc*2; off ^= (q & 7) << 4;
      *(ushort4*)(Ds + off) = o;
    }
  }
  __syncthreads();
  unsigned short* Yb = Y + ((size_t)(h*32 + bx)*768 + by*128)*128;
  #pragma unroll
  for (int it = 0; it < 8; ++it){
    int fl = it*256 + tid;
    int q = fl >> 4, chunk = fl & 15;
    int off = q*256 + chunk*16; off ^= (q & 7) << 4;
    uint4 val = *(const uint4*)(Ds + off);
    *(uint4*)(Yb + (size_t)fl*8) = val;
  }
}

// ------- K5: out[b][q][:] = (y*gate) @ wout^T via MFMA (hi/lo split) -------
__global__ __launch_bounds__(256) void k_final(
    const unsigned short* __restrict__ Y, const unsigned short* __restrict__ gate,
    const unsigned short* __restrict__ WoH, const unsigned short* __restrict__ WoL,
    float* __restrict__ out)
{
  const int p = blockIdx.x;
  const int r = p & 7, t = p >> 3;
  const int b  = r*64 + (t & 63);
  const int q0 = (t >> 6) * 64;
  const int tid = threadIdx.x, w = tid >> 6, lane = tid & 63;
  const int lr = lane & 15, lc = lane >> 4;

  short8_t bh[4][2], bl[4][2];
  #pragma unroll
  for (int nf = 0; nf < 4; ++nf){
    #pragma unroll
    for (int s = 0; s < 2; ++s){
      bh[nf][s] = *(const short8_t*)(WoH + (nf*16 + lr)*64 + s*32 + lc*8);
      bl[nf][s] = *(const short8_t*)(WoL + (nf*16 + lr)*64 + s*32 + lc*8);
    }
  }

  const int q = q0 + w*16 + lr;
  short8_t ah[2], al[2];
  #pragma unroll
  for (int s = 0; s < 2; ++s){
    const int hh = s*4 + lc;          // head = i>>3
    short8_t y8 = *(const short8_t*)(Y + ((size_t)(hh*32 + (b >> 4))*768 + q)*128 + (b & 15)*8);
    short8_t g8 = *(const short8_t*)(gate + ((size_t)b*NRES + q)*MSAC + s*32 + lc*8);
    #pragma unroll
    for (int e = 0; e < 8; ++e){
      float pp = bf2f((unsigned short)y8[e]) * bf2f((unsigned short)g8[e]);
      unsigned short hi = f2bf(pp);
      ah[s][e] = (short)hi;
      al[s][e] = (short)f2bf(pp - bf2f(hi));
    }
  }

  f32x4 acc[4];
  #pragma unroll
  for (int nf = 0; nf < 4; ++nf) acc[nf] = 0.f;
  #pragma unroll
  for (int nf = 0; nf < 4; ++nf){
    #pragma unroll
    for (int s = 0; s < 2; ++s){
      acc[nf] = __builtin_amdgcn_mfma_f32_16x16x32_bf16(ah[s], bh[nf][s], acc[nf], 0, 0, 0);
      acc[nf] = __builtin_amdgcn_mfma_f32_16x16x32_bf16(al[s], bh[nf][s], acc[nf], 0, 0, 0);
      acc[nf] = __builtin_amdgcn_mfma_f32_16x16x32_bf16(ah[s], bl[nf][s], acc[nf], 0, 0, 0);
    }
  }

  #pragma unroll
  for (int nf = 0; nf < 4; ++nf){
    #pragma unroll
    for (int e = 0; e < 4; ++e){
      int qq = q0 + w*16 + lc*4 + e;
      out[((size_t)b*NRES + qq)*MSAC + nf*16 + lr] = acc[nf][e];
    }
  }
}

extern "C" void kernel_launch(void* const* d_in, const int* in_sizes, int n_in,
                              void* d_out, int out_size, void* d_ws, size_t ws_size,
                              hipStream_t stream) {
  (void)in_sizes; (void)n_in; (void)out_size; (void)ws_size;
  const float* act    = (const float*)d_in[0];
  const float* mask   = (const float*)d_in[1];
  const float* pair   = (const float*)d_in[2];
  const float* ascale = (const float*)d_in[3];
  const float* abias  = (const float*)d_in[4];
  const float* pscale = (const float*)d_in[5];
  const float* pbias  = (const float*)d_in[6];
  const float* wl     = (const float*)d_in[7];
  const float* vproj  = (const float*)d_in[8];
  const float* wgate  = (const float*)d_in[9];
  const float* wout   = (const float*)d_in[10];
  float* out = (float*)d_out;

  char* ws = (char*)d_ws;
  float*          mbias   = (float*)(ws);                                   // 3 KB
  unsigned short* WvT     = (unsigned short*)(ws + 4096);                   // 8 KB
  unsigned short* WgT     = (unsigned short*)(ws + 12288);                  // 8 KB
  unsigned short* WoH     = (unsigned short*)(ws + 20480);                  // 8 KB
  unsigned short* WoL     = (unsigned short*)(ws + 28672);                  // 8 KB
  unsigned short* WST     = (unsigned short*)(ws + 36864);                  // 4 KB
  float*          AB      = (float*)(ws + 40960);                           // 64 B
  unsigned short* weights = (unsigned short*)(ws + 45056);                  // 9.4 MB  [h][q][k]
  unsigned short* v       = (unsigned short*)(ws + 45056 + 9437184);        // 50.3 MB [h][bc][k]
  unsigned short* gate    = (unsigned short*)(ws + 45056 + 9437184 + 50331648);       // 50.3 MB [b][k][64]
  unsigned short* y       = (unsigned short*)(ws + 45056 + 9437184 + 2*50331648ull);  // 50.3 MB [h][bx][q][cl]
  float*          logits  = (float*)(ws + 45056 + 9437184 + 3*50331648ull);           // 18.9 MB [q][h][k]

  k_prep2<<<dim3(29), dim3(256), 0, stream>>>(mask, vproj, wgate, wout,
                                              pscale, pbias, wl,
                                              mbias, WvT, WgT, WoH, WoL, WST, AB);
  k_pairact<<<dim3(9216), dim3(256), 0, stream>>>(pair, WST, AB, logits,
                                                  act, ascale, abias, WvT, WgT, v, gate);
  k_soft<<<dim3(768), dim3(256), 0, stream>>>(logits, mbias, weights);
  k_wavg<<<dim3(1536), dim3(256), 0, stream>>>(v, weights, y);
  k_final<<<dim3(6144), dim3(256), 0, stream>>>(y, gate, WoH, WoL, out);
}

// Round 18
// 300.008 us; speedup vs baseline: 1.9442x; 1.0130x over previous
//
#include <hip/hip_runtime.h>
#include <hip/hip_bf16.h>

#define NSEQ 512
#define NRES 768
#define MSAC 64
#define PAIRC 128
#define NHEAD 8

typedef __attribute__((ext_vector_type(8))) short short8_t;
typedef __attribute__((ext_vector_type(4))) float f32x4;

__device__ __forceinline__ float bf2f(unsigned short u){
  return __uint_as_float(((unsigned int)u) << 16);
}
__device__ __forceinline__ unsigned short f2bf(float f){
  unsigned int x = __float_as_uint(f);
  x += 0x7fffu + ((x >> 16) & 1u);   // RTNE
  return (unsigned short)(x >> 16);
}
// async global->LDS, 16B per lane; lds base wave-uniform (HW adds lane*16)
__device__ __forceinline__ void glds16(const void* g, void* l){
  __builtin_amdgcn_global_load_lds(
      (const __attribute__((address_space(1))) unsigned int*)g,
      (__attribute__((address_space(3))) unsigned int*)l, 16, 0, 0);
}

// -------- K0: mask max + weight prep (WvT/WgT/WoH/WoL + WST/AB for pair) --------
__global__ __launch_bounds__(256) void k_prep2(
    const float* __restrict__ mask, const float* __restrict__ vproj,
    const float* __restrict__ wgate, const float* __restrict__ wout,
    const float* __restrict__ pscale, const float* __restrict__ pbias,
    const float* __restrict__ wl,
    float* __restrict__ bias, unsigned short* __restrict__ WvT,
    unsigned short* __restrict__ WgT, unsigned short* __restrict__ WoH,
    unsigned short* __restrict__ WoL, unsigned short* __restrict__ WST,
    float* __restrict__ AB)
{
  const int bid = blockIdx.x, tid = threadIdx.x;
  if (bid < 12){
    __shared__ float red[4][64];
    const int kk = bid*64 + (tid & 63);
    const int bs = tid >> 6;
    float m = -1e30f;
    for (int b = bs; b < NSEQ; b += 4) m = fmaxf(m, mask[(size_t)b*NRES + kk]);
    red[bs][tid & 63] = m;
    __syncthreads();
    if (tid < 64){
      float mm = fmaxf(fmaxf(red[0][tid], red[1][tid]),
                       fmaxf(red[2][tid], red[3][tid]));
      bias[bid*64 + tid] = 1e9f * (bf2f(f2bf(mm)) - 1.0f);  // ref casts max to bf16
    }
  } else if (bid < 28){
    const int t = (bid - 12)*256 + tid;   // 4096 total
    const int j = t >> 6, i = t & 63;
    WvT[t] = f2bf(vproj[i*64 + j]);
    WgT[t] = f2bf(wgate[t]);
    float wv = wout[t];
    unsigned short hh = f2bf(wv);
    WoH[t] = hh;
    WoL[t] = f2bf(wv - bf2f(hh));
  } else {
    #pragma unroll
    for (int i = 0; i < 4; ++i){
      int t = i*256 + tid;              // 1024 entries
      int h = t >> 7, c = t & 127;
      float w = pscale[c] * wl[h*PAIRC + c];
      unsigned short hh = f2bf(w);
      WST[h*PAIRC + c] = hh;
      WST[(h + 8)*PAIRC + c] = f2bf(w - bf2f(hh));
    }
    const int h = tid >> 5, cc = tid & 31;
    float pa = 0.f, pb = 0.f;
    for (int c = cc; c < PAIRC; c += 32){
      float w = wl[h*PAIRC + c];
      pa += pscale[c]*w;  pb += pbias[c]*w;
    }
    #pragma unroll
    for (int m = 1; m < 32; m <<= 1){
      pa += __shfl_xor(pa, m, 64);
      pb += __shfl_xor(pb, m, 64);
    }
    if (cc == 0){ AB[h] = pa; AB[8 + h] = pb; }
  }
}

// ------- K1: merged pair + act, roles INTERLEAVED in dispatch order -------
__global__ __launch_bounds__(256) void k_pairact(
    const float* __restrict__ pair, const unsigned short* __restrict__ WST,
    const float* __restrict__ AB, float* __restrict__ logits,
    const float* __restrict__ act, const float* __restrict__ ascale,
    const float* __restrict__ abias, const unsigned short* __restrict__ WvT,
    const unsigned short* __restrict__ WgT, unsigned short* __restrict__ v,
    unsigned short* __restrict__ gate)
{
  __shared__ __align__(16) unsigned char sm[18432];   // act role: vt+gt union
  const int bid = blockIdx.x;
  const int tid = threadIdx.x;
  const int g3 = bid / 3, r3 = bid % 3;

  if (r3 == 0){
    // =================== pair role (split-K body) ===================
    const int pid = g3;
    const int q = pid >> 2;
    const int quarter = pid & 3;
    const int wv = tid >> 6, lane = tid & 63;
    const int lr = lane & 15, lcq = lane >> 4;

    short8_t wfrag[4];
    #pragma unroll
    for (int s = 0; s < 4; ++s)
      wfrag[s] = *(const short8_t*)(WST + lr*PAIRC + lcq*8 + s*32);

    const int hb = (lcq & 1) * 4;
    float A4[4], B4[4];
    #pragma unroll
    for (int r = 0; r < 4; ++r){ A4[r] = AB[hb + r]; B4[r] = AB[8 + hb + r]; }

    #pragma unroll
    for (int i = 0; i < 3; ++i){
      const int tile = quarter*12 + wv + 4*i;
      const int k0 = tile * 16;
      const float* base = pair + ((size_t)q*NRES + k0 + lr)*PAIRC + lcq*8;
      f32x4 a1 = 0.f, a2 = 0.f;
      float s = 0.f, ss = 0.f;
      #pragma unroll
      for (int st = 0; st < 4; ++st){
        float4 u0 = *(const float4*)(base + st*32);
        float4 u1 = *(const float4*)(base + st*32 + 4);
        float xv[8] = {u0.x,u0.y,u0.z,u0.w,u1.x,u1.y,u1.z,u1.w};
        short8_t xh, xl;
        #pragma unroll
        for (int e = 0; e < 8; ++e){
          s += xv[e]; ss += xv[e]*xv[e];
          unsigned short hi = f2bf(xv[e]);
          xh[e] = (short)hi;
          xl[e] = (short)f2bf(xv[e] - bf2f(hi));
        }
        a1 = __builtin_amdgcn_mfma_f32_16x16x32_bf16(wfrag[st], xh, a1, 0, 0, 0);
        a2 = __builtin_amdgcn_mfma_f32_16x16x32_bf16(wfrag[st], xl, a2, 0, 0, 0);
      }
      s  += __shfl_xor(s, 16, 64);  ss += __shfl_xor(ss, 16, 64);
      s  += __shfl_xor(s, 32, 64);  ss += __shfl_xor(ss, 32, 64);
      const float mu  = s * (1.f/128.f);
      const float var = ss * (1.f/128.f) - mu*mu;
      const float rsq = rsqrtf(var + 1e-5f);
      float d[4];
      #pragma unroll
      for (int r = 0; r < 4; ++r)
        d[r] = a1[r] + __shfl_xor(a1[r], 32, 64) + a2[r];
      if (lane < 32){
        const int k = k0 + lr;
        #pragma unroll
        for (int r = 0; r < 4; ++r)
          logits[(size_t)q*6144 + (hb + r)*768 + k] = rsq * (d[r] - mu * A4[r]) + B4[r];
      }
    }
  } else {
    // =================== act role (R8-proven 256-thr 64-row body) ===================
    unsigned short (*vt)[72] = (unsigned short (*)[72])sm;            // 9216 B
    unsigned short (*gt)[72] = (unsigned short (*)[72])(sm + 9216);   // 9216 B
    const int aid = 2*g3 + (r3 - 1);
    const int b  = aid / 12;
    const int k0 = (aid % 12) * 64;
    const int w = tid >> 6, lane = tid & 63;
    const int lr = lane & 15;
    const int lc = lane >> 4;
    const int row = k0 + w*16 + lr;

    short8_t bv[4][2], bg[4][2];
    #pragma unroll
    for (int mf = 0; mf < 4; ++mf){
      #pragma unroll
      for (int s = 0; s < 2; ++s){
        bv[mf][s] = *(const short8_t*)(WvT + (mf*16 + lr)*64 + s*32 + lc*8);
        bg[mf][s] = *(const short8_t*)(WgT + (mf*16 + lr)*64 + s*32 + lc*8);
      }
    }

    const float* arow = act + ((size_t)b*NRES + row)*MSAC;
    float x[2][8];
    #pragma unroll
    for (int s = 0; s < 2; ++s){
      float4 t0 = *(const float4*)(arow + s*32 + lc*8);
      float4 t1 = *(const float4*)(arow + s*32 + lc*8 + 4);
      x[s][0]=t0.x; x[s][1]=t0.y; x[s][2]=t0.z; x[s][3]=t0.w;
      x[s][4]=t1.x; x[s][5]=t1.y; x[s][6]=t1.z; x[s][7]=t1.w;
    }
    float ps = 0.f, pss = 0.f;
    #pragma unroll
    for (int s = 0; s < 2; ++s)
      #pragma unroll
      for (int e = 0; e < 8; ++e){ ps += x[s][e]; pss += x[s][e]*x[s][e]; }
    ps  += __shfl_xor(ps, 16, 64);  pss += __shfl_xor(pss, 16, 64);
    ps  += __shfl_xor(ps, 32, 64);  pss += __shfl_xor(pss, 32, 64);
    const float mu  = ps * (1.f/64.f);
    const float var = pss * (1.f/64.f) - mu*mu;
    const float rs  = rsqrtf(var + 1e-5f);

    short8_t a[2];
    #pragma unroll
    for (int s = 0; s < 2; ++s){
      float4 s0 = *(const float4*)(ascale + s*32 + lc*8);
      float4 s1 = *(const float4*)(ascale + s*32 + lc*8 + 4);
      float4 b0 = *(const float4*)(abias  + s*32 + lc*8);
      float4 b1 = *(const float4*)(abias  + s*32 + lc*8 + 4);
      const float sc[8] = {s0.x,s0.y,s0.z,s0.w,s1.x,s1.y,s1.z,s1.w};
      const float bs[8] = {b0.x,b0.y,b0.z,b0.w,b1.x,b1.y,b1.z,b1.w};
      #pragma unroll
      for (int e = 0; e < 8; ++e)
        a[s][e] = (short)f2bf((x[s][e] - mu)*rs*sc[e] + bs[e]);
    }

    f32x4 accv[4], accg[4];
    #pragma unroll
    for (int mf = 0; mf < 4; ++mf){ accv[mf] = 0.f; accg[mf] = 0.f; }
    #pragma unroll
    for (int mf = 0; mf < 4; ++mf){
      #pragma unroll
      for (int s = 0; s < 2; ++s){
        accv[mf] = __builtin_amdgcn_mfma_f32_16x16x32_bf16(a[s], bv[mf][s], accv[mf], 0, 0, 0);
        accg[mf] = __builtin_amdgcn_mfma_f32_16x16x32_bf16(bg[mf][s], a[s], accg[mf], 0, 0, 0);
      }
    }

    #pragma unroll
    for (int mf = 0; mf < 4; ++mf){
      ushort4 ov;
      ov.x = f2bf(accv[mf][0]); ov.y = f2bf(accv[mf][1]);
      ov.z = f2bf(accv[mf][2]); ov.w = f2bf(accv[mf][3]);
      *(ushort4*)&vt[mf*16 + lr][w*16 + lc*4] = ov;
      ushort4 og;
      og.x = f2bf(1.0f/(1.0f + __expf(-accg[mf][0])));
      og.y = f2bf(1.0f/(1.0f + __expf(-accg[mf][1])));
      og.z = f2bf(1.0f/(1.0f + __expf(-accg[mf][2])));
      og.w = f2bf(1.0f/(1.0f + __expf(-accg[mf][3])));
      *(ushort4*)&gt[w*16 + lr][mf*16 + lc*4] = og;
    }
    __syncthreads();
    #pragma unroll
    for (int it = 0; it < 2; ++it){
      int fl = it*256 + tid;
      int j = fl >> 3, chunk = fl & 7;
      uint4 val = *(const uint4*)&vt[j][chunk*8];
      *(uint4*)(v + ((size_t)(j >> 3)*4096 + (size_t)b*8 + (j & 7))*NRES + k0 + chunk*8) = val;
    }
    #pragma unroll
    for (int it = 0; it < 2; ++it){
      int fl = it*256 + tid;
      int k = fl >> 3, chunk = fl & 7;
      uint4 val = *(const uint4*)&gt[k][chunk*8];
      *(uint4*)(gate + ((size_t)b*NRES + k0 + k)*MSAC + chunk*8) = val;
    }
  }
}

// ------- K1s: softmax over k: logits[q][h][k] + mbias -> weights bf16 [h][q][k] -------
__global__ __launch_bounds__(256) void k_soft(
    const float* __restrict__ logits, const float* __restrict__ mbias,
    unsigned short* __restrict__ weights)
{
  __shared__ float lgf[6144];   // 24 KB: [h][k] for this q
  const int q = blockIdx.x, tid = threadIdx.x;
  const float* src = logits + (size_t)q*6144;
  #pragma unroll
  for (int i = 0; i < 6; ++i){
    int idx = (i*256 + tid)*4;
    *(float4*)&lgf[idx] = *(const float4*)(src + idx);
  }
  __syncthreads();
  const int wv = tid >> 6, lane = tid & 63;
  #pragma unroll
  for (int hh = 0; hh < 2; ++hh){
    int h = wv + hh*4;
    float mx = -1e30f;
    for (int kk = lane; kk < NRES; kk += 64) mx = fmaxf(mx, lgf[h*768 + kk] + mbias[kk]);
    #pragma unroll
    for (int m = 1; m < 64; m <<= 1) mx = fmaxf(mx, __shfl_xor(mx, m, 64));
    float sum = 0.f;
    for (int kk = lane; kk < NRES; kk += 64){
      float e = __expf(lgf[h*768 + kk] + mbias[kk] - mx);
      lgf[h*768 + kk] = e; sum += e;
    }
    #pragma unroll
    for (int m = 1; m < 64; m <<= 1) sum += __shfl_xor(sum, m, 64);
    float inv = 1.0f / sum;
    unsigned short* wrow = weights + ((size_t)h * NRES + q) * NRES;
    for (int kk = lane; kk < NRES; kk += 64) wrow[kk] = f2bf(lgf[h*768 + kk] * inv);
  }
}

// ------- K4: per-head GEMM  Y3[h][bx][q][cl] = weights[h] @ v[h] -------
// 3-buffer 2-deep pipeline with COUNTED vmcnt across raw barriers (T4):
// per K-step {vmcnt(4) -> s_barrier -> STAGE(kt+2) -> ds_read buf[kt] -> MFMA}.
// Prefetches stay in flight across barriers (never drain to 0 mid-loop).
__global__ __launch_bounds__(256) void k_wavg(
    const unsigned short* __restrict__ V, const unsigned short* __restrict__ W,
    unsigned short* __restrict__ Y)
{
  __shared__ unsigned char smem[49152];   // 3 bufs x (A 8K + B 8K)

  const int flat = blockIdx.x;
  const int nid  = (flat & 7) * 192 + (flat >> 3);   // XCD chunk of 192 = 1 head
  const int m    = nid % 192;
  const int by   = m % 6;              // fastest: A-tile reuse across 6 blocks
  const int bx   = m / 6;
  const int h    = nid / 192;

  const int tid = threadIdx.x, wid = tid >> 6, lane = tid & 63;
  const int wm = wid & 1, wn = wid >> 1;
  const unsigned short* Ag = V + (size_t)h*4096*768 + (size_t)bx*128*768;
  const unsigned short* Bg = W + (size_t)h*768*768 + (size_t)by*128*768;

  f32x4 acc[4][4];
  #pragma unroll
  for (int i=0;i<4;++i){
    #pragma unroll
    for (int jj=0;jj<4;++jj) acc[i][jj] = 0.f;
  }

  // 4 glds16 per thread per STAGE (2 r-iters x {A,B})
  #define STAGE_K(bufsel, kt) { \
    unsigned char* Ab = smem + (bufsel)*16384; \
    unsigned char* Bb = Ab + 8192; \
    _Pragma("unroll") \
    for (int r = 0; r < 2; ++r){ \
      int cid = tid + r*256; \
      int rw = cid >> 2, ch = cid & 3; \
      int sc = ch ^ ((rw >> 1) & 3); \
      glds16(Ag + (size_t)rw*768 + (kt)*32 + sc*8, Ab + cid*16 - lane*16); \
      glds16(Bg + (size_t)rw*768 + (kt)*32 + sc*8, Bb + cid*16 - lane*16); \
    } }

  STAGE_K(0, 0);
  STAGE_K(1, 1);
  const int c0 = lane >> 4;            // k-chunk selector
  for (int kt = 0; kt < 24; ++kt){
    // ensure STAGE(kt) landed; leave STAGE(kt+1) in flight (counted wait)
    if (kt < 23) asm volatile("s_waitcnt vmcnt(4)" ::: "memory");
    else         asm volatile("s_waitcnt vmcnt(0)" ::: "memory");
    __builtin_amdgcn_sched_barrier(0);
    __builtin_amdgcn_s_barrier();      // raw barrier: no implicit vmcnt(0) drain
    __builtin_amdgcn_sched_barrier(0);
    if (kt + 2 < 24) STAGE_K((kt+2)%3, kt+2);   // post-barrier issue: race-free
    unsigned char* Ab = smem + (kt%3)*16384;
    unsigned char* Bb = Ab + 8192;
    short8_t af[4], bf[4];
    #pragma unroll
    for (int mf = 0; mf < 4; ++mf){
      int row = wm*64 + mf*16 + (lane & 15);
      int off = row*64 + ((c0 ^ ((row>>1)&3)) << 4);
      af[mf] = *(const short8_t*)(Ab + off);
    }
    #pragma unroll
    for (int nf = 0; nf < 4; ++nf){
      int row = wn*64 + nf*16 + (lane & 15);
      int off = row*64 + ((c0 ^ ((row>>1)&3)) << 4);
      bf[nf] = *(const short8_t*)(Bb + off);
    }
    #pragma unroll
    for (int mf = 0; mf < 4; ++mf){
      #pragma unroll
      for (int nf = 0; nf < 4; ++nf)
        acc[mf][nf] = __builtin_amdgcn_mfma_f32_16x16x32_bf16(af[mf], bf[nf], acc[mf][nf], 0, 0, 0);
    }
  }
  #undef STAGE_K

  // ---- epilogue: D -> swizzled LDS (bytes 0-32K; buf2 untouched) -> stores ----
  __syncthreads();                       // all waves done with K-loop LDS reads
  unsigned char* Ds = smem;              // 32 KB: [q_local 128][bc_local 128] bf16
  #pragma unroll
  for (int mf = 0; mf < 4; ++mf){
    int bc = wm*64 + mf*16 + ((lane >> 4) << 2);
    #pragma unroll
    for (int nf = 0; nf < 4; ++nf){
      int q = wn*64 + nf*16 + (lane & 15);
      f32x4 a = acc[mf][nf];
      ushort4 o;
      o.x = f2bf(a[0]); o.y = f2bf(a[1]); o.z = f2bf(a[2]); o.w = f2bf(a[3]);
      int off = q*256 + bc*2; off ^= (q & 7) << 4;
      *(ushort4*)(Ds + off) = o;
    }
  }
  __syncthreads();
  unsigned short* Yb = Y + ((size_t)(h*32 + bx)*768 + by*128)*128;
  #pragma unroll
  for (int it = 0; it < 8; ++it){
    int fl = it*256 + tid;
    int q = fl >> 4, chunk = fl & 15;
    int off = q*256 + chunk*16; off ^= (q & 7) << 4;
    uint4 val = *(const uint4*)(Ds + off);
    *(uint4*)(Yb + (size_t)fl*8) = val;
  }
}

// ------- K5: out[b][q][:] = (y*gate) @ wout^T via MFMA (hi/lo split) -------
__global__ __launch_bounds__(256) void k_final(
    const unsigned short* __restrict__ Y, const unsigned short* __restrict__ gate,
    const unsigned short* __restrict__ WoH, const unsigned short* __restrict__ WoL,
    float* __restrict__ out)
{
  const int p = blockIdx.x;
  const int r = p & 7, t = p >> 3;
  const int b  = r*64 + (t & 63);
  const int q0 = (t >> 6) * 64;
  const int tid = threadIdx.x, w = tid >> 6, lane = tid & 63;
  const int lr = lane & 15, lc = lane >> 4;

  short8_t bh[4][2], bl[4][2];
  #pragma unroll
  for (int nf = 0; nf < 4; ++nf){
    #pragma unroll
    for (int s = 0; s < 2; ++s){
      bh[nf][s] = *(const short8_t*)(WoH + (nf*16 + lr)*64 + s*32 + lc*8);
      bl[nf][s] = *(const short8_t*)(WoL + (nf*16 + lr)*64 + s*32 + lc*8);
    }
  }

  const int q = q0 + w*16 + lr;
  short8_t ah[2], al[2];
  #pragma unroll
  for (int s = 0; s < 2; ++s){
    const int hh = s*4 + lc;          // head = i>>3
    short8_t y8 = *(const short8_t*)(Y + ((size_t)(hh*32 + (b >> 4))*768 + q)*128 + (b & 15)*8);
    short8_t g8 = *(const short8_t*)(gate + ((size_t)b*NRES + q)*MSAC + s*32 + lc*8);
    #pragma unroll
    for (int e = 0; e < 8; ++e){
      float pp = bf2f((unsigned short)y8[e]) * bf2f((unsigned short)g8[e]);
      unsigned short hi = f2bf(pp);
      ah[s][e] = (short)hi;
      al[s][e] = (short)f2bf(pp - bf2f(hi));
    }
  }

  f32x4 acc[4];
  #pragma unroll
  for (int nf = 0; nf < 4; ++nf) acc[nf] = 0.f;
  #pragma unroll
  for (int nf = 0; nf < 4; ++nf){
    #pragma unroll
    for (int s = 0; s < 2; ++s){
      acc[nf] = __builtin_amdgcn_mfma_f32_16x16x32_bf16(ah[s], bh[nf][s], acc[nf], 0, 0, 0);
      acc[nf] = __builtin_amdgcn_mfma_f32_16x16x32_bf16(al[s], bh[nf][s], acc[nf], 0, 0, 0);
      acc[nf] = __builtin_amdgcn_mfma_f32_16x16x32_bf16(ah[s], bl[nf][s], acc[nf], 0, 0, 0);
    }
  }

  #pragma unroll
  for (int nf = 0; nf < 4; ++nf){
    #pragma unroll
    for (int e = 0; e < 4; ++e){
      int qq = q0 + w*16 + lc*4 + e;
      out[((size_t)b*NRES + qq)*MSAC + nf*16 + lr] = acc[nf][e];
    }
  }
}

extern "C" void kernel_launch(void* const* d_in, const int* in_sizes, int n_in,
                              void* d_out, int out_size, void* d_ws, size_t ws_size,
                              hipStream_t stream) {
  (void)in_sizes; (void)n_in; (void)out_size; (void)ws_size;
  const float* act    = (const float*)d_in[0];
  const float* mask   = (const float*)d_in[1];
  const float* pair   = (const float*)d_in[2];
  const float* ascale = (const float*)d_in[3];
  const float* abias  = (const float*)d_in[4];
  const float* pscale = (const float*)d_in[5];
  const float* pbias  = (const float*)d_in[6];
  const float* wl     = (const float*)d_in[7];
  const float* vproj  = (const float*)d_in[8];
  const float* wgate  = (const float*)d_in[9];
  const float* wout   = (const float*)d_in[10];
  float* out = (float*)d_out;

  char* ws = (char*)d_ws;
  float*          mbias   = (float*)(ws);                                   // 3 KB
  unsigned short* WvT     = (unsigned short*)(ws + 4096);                   // 8 KB
  unsigned short* WgT     = (unsigned short*)(ws + 12288);                  // 8 KB
  unsigned short* WoH     = (unsigned short*)(ws + 20480);                  // 8 KB
  unsigned short* WoL     = (unsigned short*)(ws + 28672);                  // 8 KB
  unsigned short* WST     = (unsigned short*)(ws + 36864);                  // 4 KB
  float*          AB      = (float*)(ws + 40960);                           // 64 B
  unsigned short* weights = (unsigned short*)(ws + 45056);                  // 9.4 MB  [h][q][k]
  unsigned short* v       = (unsigned short*)(ws + 45056 + 9437184);        // 50.3 MB [h][bc][k]
  unsigned short* gate    = (unsigned short*)(ws + 45056 + 9437184 + 50331648);       // 50.3 MB [b][k][64]
  unsigned short* y       = (unsigned short*)(ws + 45056 + 9437184 + 2*50331648ull);  // 50.3 MB [h][bx][q][cl]
  float*          logits  = (float*)(ws + 45056 + 9437184 + 3*50331648ull);           // 18.9 MB [q][h][k]

  k_prep2<<<dim3(29), dim3(256), 0, stream>>>(mask, vproj, wgate, wout,
                                              pscale, pbias, wl,
                                              mbias, WvT, WgT, WoH, WoL, WST, AB);
  k_pairact<<<dim3(9216), dim3(256), 0, stream>>>(pair, WST, AB, logits,
                                                  act, ascale, abias, WvT, WgT, v, gate);
  k_soft<<<dim3(768), dim3(256), 0, stream>>>(logits, mbias, weights);
  k_wavg<<<dim3(1536), dim3(256), 0, stream>>>(v, weights, y);
  k_final<<<dim3(6144), dim3(256), 0, stream>>>(y, gate, WoH, WoL, out);
}